// Round 5
// baseline (1255.700 us; speedup 1.0000x reference)
//
#include <hip/hip_runtime.h>
#include <hip/hip_bf16.h>

typedef __attribute__((ext_vector_type(8))) short short8;
typedef __attribute__((ext_vector_type(4))) float f32x4;
typedef __attribute__((ext_vector_type(4))) unsigned int uint4v;
typedef unsigned short u16;

#define MFMA_BF16(a, b, c) __builtin_amdgcn_mfma_f32_16x16x32_bf16(a, b, c, 0, 0, 0)

#define T_SEQ 2048
#define DMODEL 1024
#define NHEADS 16
#define DHEAD 64
#define NEG_BIG (-30000.0f)

// fp32 bits -> bf16 bits, round-to-nearest-even
__device__ __forceinline__ unsigned bfr(unsigned u) {
  return (u + 0x7fffu + ((u >> 16) & 1u)) >> 16;
}
// load 8 consecutive fp32, return 8 packed bf16 (as uint4v for 16B LDS store)
__device__ __forceinline__ uint4v ld8bf(const float* __restrict__ p) {
  const uint4v a = *(const uint4v*)p;
  const uint4v b = *(const uint4v*)(p + 4);
  uint4v r;
  r[0] = bfr(a[0]) | (bfr(a[1]) << 16);
  r[1] = bfr(a[2]) | (bfr(a[3]) << 16);
  r[2] = bfr(b[0]) | (bfr(b[1]) << 16);
  r[3] = bfr(b[2]) | (bfr(b[3]) << 16);
  return r;
}
__device__ __forceinline__ u16 f2bf(float f) {
  unsigned u = __float_as_uint(f);
  u += 0x7fffu + ((u >> 16) & 1u);
  return (u16)(u >> 16);
}

// ---------------------------------------------------------------- attention
// grid (16, 32): x = reversed Q-tile (128 rows), y = bh = b*16+h. 256 thr = 4 waves.
// Fully fused: Q-proj, per-kv-tile K/V-proj (recomputed, zero global scratch),
// online-softmax attention. O written fp32 to Og = d_out, layout (b,t,h*64+d).
__global__ __launch_bounds__(256) void attn_fused(
    const float* __restrict__ X, const float* __restrict__ Wq,
    const float* __restrict__ Wk, const float* __restrict__ Wv,
    float* __restrict__ Og) {
  __shared__ u16 smem[27648];  // 55296 B
  u16* Qs = smem;              // 128*72 (scaled Q, bf16)
  u16* Ks = smem + 9216;       // 64*72
  u16* Vt = smem + 13824;      // 64*72 (V transposed: Vt[d][kv])
  u16* Ps = smem + 18432;      // 128*72
  // phase aliases:
  u16* xs = Ks;                // Q-proj x staging 128x32
  u16* wqs = Vt;               // Q-proj Wq staging 64x32
  u16* xkv = Ps;               // KV-proj x staging 64x32
  u16* wks = Ps + 2048;        // KV-proj Wk staging 64x32
  u16* wvs = Ps + 4096;        // KV-proj Wv staging 64x32

  const int tid = threadIdx.x;
  const int w = tid >> 6, lane = tid & 63;
  const int lrow = lane & 15;
  const int lk = (lane >> 4) << 3;  // k-offset in A/B fragments
  const int lq = (lane >> 4) << 2;  // row-group offset in C layout

  const int qt = gridDim.x - 1 - blockIdx.x;  // heavy blocks first
  const int qb = qt * 128;
  const int bh = blockIdx.y;
  const int b = bh >> 4, h = bh & 15;
  const float* xp = X + (size_t)b * T_SEQ * DMODEL;
  const float* wqp = Wq + (size_t)h * DHEAD * DMODEL;
  const float* wkp = Wk + (size_t)h * DHEAD * DMODEL;
  const float* wvp = Wv + (size_t)h * DHEAD * DMODEL;

  // ---- fused Q projection: wave computes 32 q-rows x 64 d
  f32x4 qacc[2][4];
#pragma unroll
  for (int mi = 0; mi < 2; mi++)
#pragma unroll
    for (int nd = 0; nd < 4; nd++) qacc[mi][nd] = (f32x4)0.0f;

  for (int k0 = 0; k0 < 1024; k0 += 32) {
    __syncthreads();
#pragma unroll
    for (int i = 0; i < 2; i++) {  // xs: 128 rows x 32 cols
      int c = i * 256 + tid;
      int r = c >> 2, kk = (c & 3) << 3;
      *(uint4v*)&xs[r * 32 + kk] = ld8bf(&xp[(size_t)(qb + r) * 1024 + k0 + kk]);
    }
    {  // wqs: 64 rows x 32 cols
      int r = tid >> 2, kk = (tid & 3) << 3;
      *(uint4v*)&wqs[r * 32 + kk] = ld8bf(&wqp[(size_t)r * 1024 + k0 + kk]);
    }
    __syncthreads();
    short8 bfrag[4];
#pragma unroll
    for (int nd = 0; nd < 4; nd++)
      bfrag[nd] = *(const short8*)&wqs[(nd * 16 + lrow) * 32 + lk];
#pragma unroll
    for (int mi = 0; mi < 2; mi++) {
      short8 af = *(const short8*)&xs[(w * 32 + mi * 16 + lrow) * 32 + lk];
#pragma unroll
      for (int nd = 0; nd < 4; nd++)
        qacc[mi][nd] = MFMA_BF16(af, bfrag[nd], qacc[mi][nd]);
    }
  }
  __syncthreads();
  // write scaled Q (bf16) into Qs, C-layout -> row-major (own-wave strip)
#pragma unroll
  for (int mi = 0; mi < 2; mi++)
#pragma unroll
    for (int r = 0; r < 4; r++)
#pragma unroll
      for (int nd = 0; nd < 4; nd++)
        Qs[(w * 32 + mi * 16 + lq + r) * 72 + nd * 16 + lrow] =
            f2bf(qacc[mi][nd][r] * 0.125f);
  short8 qf[2][2];
#pragma unroll
  for (int mi = 0; mi < 2; mi++)
#pragma unroll
    for (int ks = 0; ks < 2; ks++)
      qf[mi][ks] =
          *(const short8*)&Qs[(w * 32 + mi * 16 + lrow) * 72 + ks * 32 + lk];

  float mst[2][4], lst[2][4];
  f32x4 oacc[2][4];
#pragma unroll
  for (int mi = 0; mi < 2; mi++) {
#pragma unroll
    for (int r = 0; r < 4; r++) { mst[mi][r] = NEG_BIG; lst[mi][r] = 0.f; }
#pragma unroll
    for (int nd = 0; nd < 4; nd++) oacc[mi][nd] = (f32x4)0.0f;
  }

  const int ntiles = qt * 2 + 2;
  for (int kt = 0; kt < ntiles; kt++) {
    const int kvb = kt * 64;

    // ---- fused K/V projection of this 64-row kv tile (wave: 16 kv-rows x 64 d)
    f32x4 kacc[4], vacc[4];
#pragma unroll
    for (int nd = 0; nd < 4; nd++) { kacc[nd] = (f32x4)0.0f; vacc[nd] = (f32x4)0.0f; }
    for (int k0 = 0; k0 < 1024; k0 += 32) {
      __syncthreads();  // also guards Ps-region reuse from previous iteration
      {
        int r = tid >> 2, kk = (tid & 3) << 3;
        *(uint4v*)&xkv[r * 32 + kk] = ld8bf(&xp[(size_t)(kvb + r) * 1024 + k0 + kk]);
        *(uint4v*)&wks[r * 32 + kk] = ld8bf(&wkp[(size_t)r * 1024 + k0 + kk]);
        *(uint4v*)&wvs[r * 32 + kk] = ld8bf(&wvp[(size_t)r * 1024 + k0 + kk]);
      }
      __syncthreads();
      short8 af = *(const short8*)&xkv[(w * 16 + lrow) * 32 + lk];
#pragma unroll
      for (int nd = 0; nd < 4; nd++) {
        short8 bk = *(const short8*)&wks[(nd * 16 + lrow) * 32 + lk];
        short8 bv = *(const short8*)&wvs[(nd * 16 + lrow) * 32 + lk];
        kacc[nd] = MFMA_BF16(af, bk, kacc[nd]);
        vacc[nd] = MFMA_BF16(af, bv, vacc[nd]);
      }
    }
    // scatter results: Ks[kv][d] row-major, Vt[d][kv] transposed
#pragma unroll
    for (int nd = 0; nd < 4; nd++)
#pragma unroll
      for (int r = 0; r < 4; r++) {
        Ks[(w * 16 + lq + r) * 72 + nd * 16 + lrow] = f2bf(kacc[nd][r]);
        Vt[(nd * 16 + lrow) * 72 + w * 16 + lq + r] = f2bf(vacc[nd][r]);
      }
    __syncthreads();

    // ---- S = Q K^T (per wave: 32 x 64); Q pre-scaled by 1/8
    f32x4 s[2][4];
#pragma unroll
    for (int mi = 0; mi < 2; mi++)
#pragma unroll
      for (int nt = 0; nt < 4; nt++) {
        f32x4 a = (f32x4)0.0f;
#pragma unroll
        for (int ks = 0; ks < 2; ks++) {
          short8 kf = *(const short8*)&Ks[(nt * 16 + lrow) * 72 + ks * 32 + lk];
          a = MFMA_BF16(qf[mi][ks], kf, a);
        }
        s[mi][nt] = a;
      }

    // ---- online softmax (stats replicated across each 16-lane quad)
#pragma unroll
    for (int mi = 0; mi < 2; mi++) {
      int rowb = qb + w * 32 + mi * 16 + lq;
      float corr[4], lt[4];
#pragma unroll
      for (int r = 0; r < 4; r++) {
        float mx = NEG_BIG;
#pragma unroll
        for (int nt = 0; nt < 4; nt++) {
          int col = kvb + nt * 16 + lrow;
          float sv = s[mi][nt][r];
          if (col > rowb + r) sv = NEG_BIG;
          s[mi][nt][r] = sv;
          mx = fmaxf(mx, sv);
        }
#pragma unroll
        for (int off = 8; off >= 1; off >>= 1)
          mx = fmaxf(mx, __shfl_xor(mx, off));  // stays inside 16-lane quad
        float mn = fmaxf(mst[mi][r], mx);
        corr[r] = __expf(mst[mi][r] - mn);
        mst[mi][r] = mn;
        float ls = 0.f;
#pragma unroll
        for (int nt = 0; nt < 4; nt++) {
          float p = __expf(s[mi][nt][r] - mn);
          s[mi][nt][r] = p;
          ls += p;
        }
#pragma unroll
        for (int off = 8; off >= 1; off >>= 1) ls += __shfl_xor(ls, off);
        lt[r] = ls;
      }
#pragma unroll
      for (int r = 0; r < 4; r++) {
        lst[mi][r] = corr[r] * lst[mi][r] + lt[r];
#pragma unroll
        for (int nd = 0; nd < 4; nd++) oacc[mi][nd][r] *= corr[r];
#pragma unroll
        for (int nt = 0; nt < 4; nt++)
          Ps[(w * 32 + mi * 16 + lq + r) * 72 + nt * 16 + lrow] =
              f2bf(s[mi][nt][r]);
      }
    }

    // ---- O += P @ V (P wave-private; same-wave LDS ordering)
#pragma unroll
    for (int ks = 0; ks < 2; ks++) {
      short8 vf[4];
#pragma unroll
      for (int nd = 0; nd < 4; nd++)
        vf[nd] = *(const short8*)&Vt[(nd * 16 + lrow) * 72 + ks * 32 + lk];
#pragma unroll
      for (int mi = 0; mi < 2; mi++) {
        short8 pf =
            *(const short8*)&Ps[(w * 32 + mi * 16 + lrow) * 72 + ks * 32 + lk];
#pragma unroll
        for (int nd = 0; nd < 4; nd++)
          oacc[mi][nd] = MFMA_BF16(pf, vf[nd], oacc[mi][nd]);
      }
    }
  }

  // ---- normalize + write O (b, t, h*64+d) fp32 into d_out
#pragma unroll
  for (int mi = 0; mi < 2; mi++)
#pragma unroll
    for (int r = 0; r < 4; r++) {
      int t = qb + w * 32 + mi * 16 + lq + r;
      float inv = 1.f / lst[mi][r];
#pragma unroll
      for (int nd = 0; nd < 4; nd++) {
        int dd = nd * 16 + lrow;
        Og[((size_t)(b * T_SEQ + t)) * DMODEL + h * DHEAD + dd] =
            oacc[mi][nd][r] * inv;
      }
    }
}

// ---------------------------------------------------------------- out proj, in place
// out = O @ Wo^T, overwriting fp32 d_out. grid 256 blocks x 16 rows. Each block
// stages its full 16x1024 O-slab (as bf16) into LDS BEFORE any write, so
// in-place is race-free (blocks own disjoint rows).
__global__ __launch_bounds__(256) void oproj_inplace(float* __restrict__ IO,
                                                     const float* __restrict__ Wo) {
  __shared__ u16 Os[16 * 1024];  // 32 KB, XOR-swizzled
  __shared__ u16 Bs[128 * 32];   // 8 KB
  const int tid = threadIdx.x, lane = tid & 63, w = tid >> 6;
  const int lrow = lane & 15;
  const int lk = (lane >> 4) << 3;
  const int lq = (lane >> 4) << 2;
  const int mBase = blockIdx.x * 16;

  // stage O slab with per-row XOR swizzle on 8-elem blocks
#pragma unroll
  for (int i = 0; i < 8; i++) {
    int c = i * 256 + tid;
    int row = c >> 7, kb = c & 127;
    *(uint4v*)&Os[row * 1024 + ((kb ^ (row & 7)) << 3)] =
        ld8bf(&IO[(size_t)(mBase + row) * 1024 + (kb << 3)]);
  }
  __syncthreads();

  for (int nt = 0; nt < 8; nt++) {
    f32x4 acc[2];
    acc[0] = (f32x4)0.0f;
    acc[1] = (f32x4)0.0f;
    for (int k0 = 0; k0 < 1024; k0 += 32) {
      __syncthreads();
#pragma unroll
      for (int i = 0; i < 2; i++) {
        int c = i * 256 + tid;
        int r = c >> 2, kk = (c & 3) << 3;
        *(uint4v*)&Bs[r * 32 + kk] =
            ld8bf(&Wo[(size_t)(nt * 128 + r) * 1024 + k0 + kk]);
      }
      __syncthreads();
      short8 af = *(const short8*)
          &Os[lrow * 1024 + ((((k0 + lk) >> 3) ^ (lrow & 7)) << 3)];
#pragma unroll
      for (int ni = 0; ni < 2; ni++) {
        short8 bf = *(const short8*)&Bs[(w * 32 + ni * 16 + lrow) * 32 + lk];
        acc[ni] = MFMA_BF16(af, bf, acc[ni]);
      }
    }
#pragma unroll
    for (int ni = 0; ni < 2; ni++)
#pragma unroll
      for (int r = 0; r < 4; r++)
        IO[(size_t)(mBase + lq + r) * 1024 + nt * 128 + w * 32 + ni * 16 +
           lrow] = acc[ni][r];
  }
}

// ---------------------------------------------------------------- launch
extern "C" void kernel_launch(void* const* d_in, const int* in_sizes, int n_in,
                              void* d_out, int out_size, void* d_ws,
                              size_t ws_size, hipStream_t stream) {
  const float* x = (const float*)d_in[0];
  const float* Wq = (const float*)d_in[1];
  const float* Wk = (const float*)d_in[2];
  const float* Wv = (const float*)d_in[3];
  const float* Wo = (const float*)d_in[4];
  float* out = (float*)d_out;
  (void)d_ws; (void)ws_size;  // deliberately unused until correctness locks

  attn_fused<<<dim3(16, 32), 256, 0, stream>>>(x, Wq, Wk, Wv, out);
  oproj_inplace<<<dim3(256), 256, 0, stream>>>(out, Wo);
}

// Round 6
// 321.422 us; speedup vs baseline: 3.9067x; 3.9067x over previous
//
#include <hip/hip_runtime.h>
#include <hip/hip_bf16.h>

typedef __attribute__((ext_vector_type(8))) short short8;
typedef __attribute__((ext_vector_type(4))) float f32x4;
typedef __attribute__((ext_vector_type(2))) unsigned int uint2v;
typedef __attribute__((ext_vector_type(4))) unsigned int uint4v;
typedef unsigned short u16;

#define MFMA_BF16(a, b, c) __builtin_amdgcn_mfma_f32_16x16x32_bf16(a, b, c, 0, 0, 0)

#define T_SEQ 2048
#define DMODEL 1024
#define NHEADS 16
#define DHEAD 64
#define NEG_BIG (-30000.0f)

// fp32 bits -> bf16 bits, round-to-nearest-even
__device__ __forceinline__ unsigned bfr(unsigned u) {
  return (u + 0x7fffu + ((u >> 16) & 1u)) >> 16;
}
// load 8 consecutive fp32, return 8 packed bf16
__device__ __forceinline__ uint4v ld8bf(const float* __restrict__ p) {
  const uint4v a = *(const uint4v*)p;
  const uint4v b = *(const uint4v*)(p + 4);
  uint4v r;
  r[0] = bfr(a[0]) | (bfr(a[1]) << 16);
  r[1] = bfr(a[2]) | (bfr(a[3]) << 16);
  r[2] = bfr(b[0]) | (bfr(b[1]) << 16);
  r[3] = bfr(b[2]) | (bfr(b[3]) << 16);
  return r;
}
__device__ __forceinline__ u16 f2bf(float f) {
  unsigned u = __float_as_uint(f);
  u += 0x7fffu + ((u >> 16) & 1u);
  return (u16)(u >> 16);
}

// ================================================================ TIER A
// ---------------------------------------------------------------- K,V proj
// K/V = x @ W^T, scatter to (b,h,t,64) bf16 in ws. grid (32,8,2): z=0 K, z=1 V.
// 128x128 tile, 4 waves (2x2), 4x4 MFMA tiles/wave, BK=32.
__global__ __launch_bounds__(256) void gemm_kv(
    const float* __restrict__ X, const float* __restrict__ Wk,
    const float* __restrict__ Wv, u16* __restrict__ Ko, u16* __restrict__ Vo) {
  __shared__ u16 As[128 * 32];
  __shared__ u16 Bs[128 * 32];
  const int tid = threadIdx.x, lane = tid & 63, w = tid >> 6;
  const int wm = (w >> 1) * 64, wn = (w & 1) * 64;
  const int lrow = lane & 15;
  const int lk = (lane >> 4) << 3;
  const int lq = (lane >> 4) << 2;
  const int mBase = blockIdx.x * 128, nBase = blockIdx.y * 128;
  const float* Bt = (blockIdx.z == 0) ? Wk : Wv;
  u16* D = (blockIdx.z == 0) ? Ko : Vo;

  f32x4 acc[4][4];
#pragma unroll
  for (int mi = 0; mi < 4; mi++)
#pragma unroll
    for (int ni = 0; ni < 4; ni++) acc[mi][ni] = (f32x4)0.0f;

  for (int k0 = 0; k0 < 1024; k0 += 32) {
    __syncthreads();
#pragma unroll
    for (int i = 0; i < 2; i++) {
      int c = i * 256 + tid;
      int r = c >> 2, kk = (c & 3) << 3;
      *(uint4v*)&As[c * 8] = ld8bf(&X[(size_t)(mBase + r) * 1024 + k0 + kk]);
      *(uint4v*)&Bs[c * 8] = ld8bf(&Bt[(size_t)(nBase + r) * 1024 + k0 + kk]);
    }
    __syncthreads();
    short8 af[4], bf[4];
#pragma unroll
    for (int mi = 0; mi < 4; mi++)
      af[mi] = *(const short8*)&As[(wm + mi * 16 + lrow) * 32 + lk];
#pragma unroll
    for (int ni = 0; ni < 4; ni++)
      bf[ni] = *(const short8*)&Bs[(wn + ni * 16 + lrow) * 32 + lk];
#pragma unroll
    for (int mi = 0; mi < 4; mi++)
#pragma unroll
      for (int ni = 0; ni < 4; ni++)
        acc[mi][ni] = MFMA_BF16(af[mi], bf[ni], acc[mi][ni]);
  }
#pragma unroll
  for (int mi = 0; mi < 4; mi++)
#pragma unroll
    for (int r = 0; r < 4; r++) {
      int m = mBase + wm + mi * 16 + lq + r;
      int b = m >> 11, t = m & 2047;
#pragma unroll
      for (int ni = 0; ni < 4; ni++) {
        int n = nBase + wn + ni * 16 + lrow;
        int h = n >> 6, dd = n & 63;
        D[(((size_t)(b * NHEADS + h)) * T_SEQ + t) * DHEAD + dd] =
            f2bf(acc[mi][ni][r]);
      }
    }
}

// ---------------------------------------------------------------- attention
// grid (16, 32). Fused Q-proj; K/V read from ws (bf16). O -> ws bf16 (b,t,h*64+d).
__global__ __launch_bounds__(256) void attn_fq(
    const float* __restrict__ X, const float* __restrict__ Wq,
    const u16* __restrict__ Kg, const u16* __restrict__ Vg,
    u16* __restrict__ Ob) {
  __shared__ u16 smem[27648];
  u16* Qs = smem;              // 128*72
  u16* Ks = smem + 9216;       // 64*72
  u16* Vt = smem + 13824;      // 64*72
  u16* Ps = smem + 18432;      // 128*72
  u16* xs = Ks;                // Q-proj x staging 128x32
  u16* wqs = Vt;               // Q-proj Wq staging 64x32

  const int tid = threadIdx.x;
  const int w = tid >> 6, lane = tid & 63;
  const int lrow = lane & 15;
  const int lk = (lane >> 4) << 3;
  const int lq = (lane >> 4) << 2;

  const int qt = gridDim.x - 1 - blockIdx.x;
  const int qb = qt * 128;
  const int bh = blockIdx.y;
  const int b = bh >> 4, h = bh & 15;
  const float* xp = X + (size_t)b * T_SEQ * DMODEL;
  const float* wqp = Wq + (size_t)h * DHEAD * DMODEL;
  const u16* Kp = Kg + (size_t)bh * T_SEQ * DHEAD;
  const u16* Vp = Vg + (size_t)bh * T_SEQ * DHEAD;

  // ---- fused Q projection: wave computes 32 q-rows x 64 d
  f32x4 qacc[2][4];
#pragma unroll
  for (int mi = 0; mi < 2; mi++)
#pragma unroll
    for (int nd = 0; nd < 4; nd++) qacc[mi][nd] = (f32x4)0.0f;

  for (int k0 = 0; k0 < 1024; k0 += 32) {
    __syncthreads();
#pragma unroll
    for (int i = 0; i < 2; i++) {
      int c = i * 256 + tid;
      int r = c >> 2, kk = (c & 3) << 3;
      *(uint4v*)&xs[r * 32 + kk] = ld8bf(&xp[(size_t)(qb + r) * 1024 + k0 + kk]);
    }
    {
      int r = tid >> 2, kk = (tid & 3) << 3;
      *(uint4v*)&wqs[r * 32 + kk] = ld8bf(&wqp[(size_t)r * 1024 + k0 + kk]);
    }
    __syncthreads();
    short8 bfrag[4];
#pragma unroll
    for (int nd = 0; nd < 4; nd++)
      bfrag[nd] = *(const short8*)&wqs[(nd * 16 + lrow) * 32 + lk];
#pragma unroll
    for (int mi = 0; mi < 2; mi++) {
      short8 af = *(const short8*)&xs[(w * 32 + mi * 16 + lrow) * 32 + lk];
#pragma unroll
      for (int nd = 0; nd < 4; nd++)
        qacc[mi][nd] = MFMA_BF16(af, bfrag[nd], qacc[mi][nd]);
    }
  }
  __syncthreads();
#pragma unroll
  for (int mi = 0; mi < 2; mi++)
#pragma unroll
    for (int r = 0; r < 4; r++)
#pragma unroll
      for (int nd = 0; nd < 4; nd++)
        Qs[(w * 32 + mi * 16 + lq + r) * 72 + nd * 16 + lrow] =
            f2bf(qacc[mi][nd][r] * 0.125f);
  short8 qf[2][2];
#pragma unroll
  for (int mi = 0; mi < 2; mi++)
#pragma unroll
    for (int ks = 0; ks < 2; ks++)
      qf[mi][ks] =
          *(const short8*)&Qs[(w * 32 + mi * 16 + lrow) * 72 + ks * 32 + lk];

  float mst[2][4], lst[2][4];
  f32x4 oacc[2][4];
#pragma unroll
  for (int mi = 0; mi < 2; mi++) {
#pragma unroll
    for (int r = 0; r < 4; r++) { mst[mi][r] = NEG_BIG; lst[mi][r] = 0.f; }
#pragma unroll
    for (int nd = 0; nd < 4; nd++) oacc[mi][nd] = (f32x4)0.0f;
  }

  const int ntiles = qt * 2 + 2;
  for (int kt = 0; kt < ntiles; kt++) {
    const int kvb = kt * 64;
    __syncthreads();  // prior readers of Ks/Vt/Ps done (also Q-proj aliases)
    // stage K tile (64x64) bf16 direct
#pragma unroll
    for (int i = 0; i < 2; i++) {
      int c = i * 256 + tid;
      int r = c >> 3, kk = (c & 7) << 3;
      *(uint4v*)&Ks[r * 72 + kk] =
          *(const uint4v*)&Kp[(size_t)(kvb + r) * DHEAD + kk];
    }
    // stage V transposed: Vt[d][kv]
#pragma unroll
    for (int i = 0; i < 4; i++) {
      int q = i * 256 + tid;
      int r = q >> 4, cc = (q & 15) << 2;
      uint2v v = *(const uint2v*)&Vp[(size_t)(kvb + r) * DHEAD + cc];
      Vt[(cc + 0) * 72 + r] = (u16)(v[0] & 0xffffu);
      Vt[(cc + 1) * 72 + r] = (u16)(v[0] >> 16);
      Vt[(cc + 2) * 72 + r] = (u16)(v[1] & 0xffffu);
      Vt[(cc + 3) * 72 + r] = (u16)(v[1] >> 16);
    }
    __syncthreads();

    // S = Q K^T (wave: 32x64)
    f32x4 s[2][4];
#pragma unroll
    for (int mi = 0; mi < 2; mi++)
#pragma unroll
      for (int nt = 0; nt < 4; nt++) {
        f32x4 a = (f32x4)0.0f;
#pragma unroll
        for (int ks = 0; ks < 2; ks++) {
          short8 kf = *(const short8*)&Ks[(nt * 16 + lrow) * 72 + ks * 32 + lk];
          a = MFMA_BF16(qf[mi][ks], kf, a);
        }
        s[mi][nt] = a;
      }

    // online softmax
#pragma unroll
    for (int mi = 0; mi < 2; mi++) {
      int rowb = qb + w * 32 + mi * 16 + lq;
      float corr[4], lt[4];
#pragma unroll
      for (int r = 0; r < 4; r++) {
        float mx = NEG_BIG;
#pragma unroll
        for (int nt = 0; nt < 4; nt++) {
          int col = kvb + nt * 16 + lrow;
          float sv = s[mi][nt][r];
          if (col > rowb + r) sv = NEG_BIG;
          s[mi][nt][r] = sv;
          mx = fmaxf(mx, sv);
        }
#pragma unroll
        for (int off = 8; off >= 1; off >>= 1)
          mx = fmaxf(mx, __shfl_xor(mx, off));
        float mn = fmaxf(mst[mi][r], mx);
        corr[r] = __expf(mst[mi][r] - mn);
        mst[mi][r] = mn;
        float ls = 0.f;
#pragma unroll
        for (int nt = 0; nt < 4; nt++) {
          float p = __expf(s[mi][nt][r] - mn);
          s[mi][nt][r] = p;
          ls += p;
        }
#pragma unroll
        for (int off = 8; off >= 1; off >>= 1) ls += __shfl_xor(ls, off);
        lt[r] = ls;
      }
#pragma unroll
      for (int r = 0; r < 4; r++) {
        lst[mi][r] = corr[r] * lst[mi][r] + lt[r];
#pragma unroll
        for (int nd = 0; nd < 4; nd++) oacc[mi][nd][r] *= corr[r];
#pragma unroll
        for (int nt = 0; nt < 4; nt++)
          Ps[(w * 32 + mi * 16 + lq + r) * 72 + nt * 16 + lrow] =
              f2bf(s[mi][nt][r]);
      }
    }

    // O += P @ V
#pragma unroll
    for (int ks = 0; ks < 2; ks++) {
      short8 vf[4];
#pragma unroll
      for (int nd = 0; nd < 4; nd++)
        vf[nd] = *(const short8*)&Vt[(nd * 16 + lrow) * 72 + ks * 32 + lk];
#pragma unroll
      for (int mi = 0; mi < 2; mi++) {
        short8 pf =
            *(const short8*)&Ps[(w * 32 + mi * 16 + lrow) * 72 + ks * 32 + lk];
#pragma unroll
        for (int nd = 0; nd < 4; nd++)
          oacc[mi][nd] = MFMA_BF16(pf, vf[nd], oacc[mi][nd]);
      }
    }
  }

  // normalize + write O bf16 (b, t, h*64+d) into ws
#pragma unroll
  for (int mi = 0; mi < 2; mi++)
#pragma unroll
    for (int r = 0; r < 4; r++) {
      int t = qb + w * 32 + mi * 16 + lq + r;
      float inv = 1.f / lst[mi][r];
#pragma unroll
      for (int nd = 0; nd < 4; nd++) {
        int dd = nd * 16 + lrow;
        Ob[((size_t)(b * T_SEQ + t)) * DMODEL + h * DHEAD + dd] =
            f2bf(oacc[mi][nd][r] * inv);
      }
    }
}

// ---------------------------------------------------------------- out proj
// out = O(bf16,ws) @ Wo^T -> fp32 d_out. grid (32, 8). 128x128 tile.
__global__ __launch_bounds__(256) void gemm_out(const u16* __restrict__ O,
                                                const float* __restrict__ Wo,
                                                float* __restrict__ Out) {
  __shared__ u16 As[128 * 32];
  __shared__ u16 Bs[128 * 32];
  const int tid = threadIdx.x, lane = tid & 63, w = tid >> 6;
  const int wm = (w >> 1) * 64, wn = (w & 1) * 64;
  const int lrow = lane & 15;
  const int lk = (lane >> 4) << 3;
  const int lq = (lane >> 4) << 2;
  const int mBase = blockIdx.x * 128, nBase = blockIdx.y * 128;

  f32x4 acc[4][4];
#pragma unroll
  for (int mi = 0; mi < 4; mi++)
#pragma unroll
    for (int ni = 0; ni < 4; ni++) acc[mi][ni] = (f32x4)0.0f;

  for (int k0 = 0; k0 < 1024; k0 += 32) {
    __syncthreads();
#pragma unroll
    for (int i = 0; i < 2; i++) {
      int c = i * 256 + tid;
      int r = c >> 2, kk = (c & 3) << 3;
      *(uint4v*)&As[c * 8] =
          *(const uint4v*)&O[(size_t)(mBase + r) * 1024 + k0 + kk];
      *(uint4v*)&Bs[c * 8] = ld8bf(&Wo[(size_t)(nBase + r) * 1024 + k0 + kk]);
    }
    __syncthreads();
    short8 af[4], bf[4];
#pragma unroll
    for (int mi = 0; mi < 4; mi++)
      af[mi] = *(const short8*)&As[(wm + mi * 16 + lrow) * 32 + lk];
#pragma unroll
    for (int ni = 0; ni < 4; ni++)
      bf[ni] = *(const short8*)&Bs[(wn + ni * 16 + lrow) * 32 + lk];
#pragma unroll
    for (int mi = 0; mi < 4; mi++)
#pragma unroll
      for (int ni = 0; ni < 4; ni++)
        acc[mi][ni] = MFMA_BF16(af[mi], bf[ni], acc[mi][ni]);
  }
#pragma unroll
  for (int mi = 0; mi < 4; mi++)
#pragma unroll
    for (int r = 0; r < 4; r++) {
      int m = mBase + wm + mi * 16 + lq + r;
#pragma unroll
      for (int ni = 0; ni < 4; ni++)
        Out[(size_t)m * DMODEL + nBase + wn + ni * 16 + lrow] =
            acc[mi][ni][r];
    }
}

// ================================================================ TIER B
// (round-5 validated fallback: zero-ws fused attention + in-place out proj)
__global__ __launch_bounds__(256) void attn_fused(
    const float* __restrict__ X, const float* __restrict__ Wq,
    const float* __restrict__ Wk, const float* __restrict__ Wv,
    float* __restrict__ Og) {
  __shared__ u16 smem[27648];
  u16* Qs = smem;
  u16* Ks = smem + 9216;
  u16* Vt = smem + 13824;
  u16* Ps = smem + 18432;
  u16* xs = Ks;
  u16* wqs = Vt;
  u16* xkv = Ps;
  u16* wks = Ps + 2048;
  u16* wvs = Ps + 4096;

  const int tid = threadIdx.x;
  const int w = tid >> 6, lane = tid & 63;
  const int lrow = lane & 15;
  const int lk = (lane >> 4) << 3;
  const int lq = (lane >> 4) << 2;

  const int qt = gridDim.x - 1 - blockIdx.x;
  const int qb = qt * 128;
  const int bh = blockIdx.y;
  const int b = bh >> 4, h = bh & 15;
  const float* xp = X + (size_t)b * T_SEQ * DMODEL;
  const float* wqp = Wq + (size_t)h * DHEAD * DMODEL;
  const float* wkp = Wk + (size_t)h * DHEAD * DMODEL;
  const float* wvp = Wv + (size_t)h * DHEAD * DMODEL;

  f32x4 qacc[2][4];
#pragma unroll
  for (int mi = 0; mi < 2; mi++)
#pragma unroll
    for (int nd = 0; nd < 4; nd++) qacc[mi][nd] = (f32x4)0.0f;

  for (int k0 = 0; k0 < 1024; k0 += 32) {
    __syncthreads();
#pragma unroll
    for (int i = 0; i < 2; i++) {
      int c = i * 256 + tid;
      int r = c >> 2, kk = (c & 3) << 3;
      *(uint4v*)&xs[r * 32 + kk] = ld8bf(&xp[(size_t)(qb + r) * 1024 + k0 + kk]);
    }
    {
      int r = tid >> 2, kk = (tid & 3) << 3;
      *(uint4v*)&wqs[r * 32 + kk] = ld8bf(&wqp[(size_t)r * 1024 + k0 + kk]);
    }
    __syncthreads();
    short8 bfrag[4];
#pragma unroll
    for (int nd = 0; nd < 4; nd++)
      bfrag[nd] = *(const short8*)&wqs[(nd * 16 + lrow) * 32 + lk];
#pragma unroll
    for (int mi = 0; mi < 2; mi++) {
      short8 af = *(const short8*)&xs[(w * 32 + mi * 16 + lrow) * 32 + lk];
#pragma unroll
      for (int nd = 0; nd < 4; nd++)
        qacc[mi][nd] = MFMA_BF16(af, bfrag[nd], qacc[mi][nd]);
    }
  }
  __syncthreads();
#pragma unroll
  for (int mi = 0; mi < 2; mi++)
#pragma unroll
    for (int r = 0; r < 4; r++)
#pragma unroll
      for (int nd = 0; nd < 4; nd++)
        Qs[(w * 32 + mi * 16 + lq + r) * 72 + nd * 16 + lrow] =
            f2bf(qacc[mi][nd][r] * 0.125f);
  short8 qf[2][2];
#pragma unroll
  for (int mi = 0; mi < 2; mi++)
#pragma unroll
    for (int ks = 0; ks < 2; ks++)
      qf[mi][ks] =
          *(const short8*)&Qs[(w * 32 + mi * 16 + lrow) * 72 + ks * 32 + lk];

  float mst[2][4], lst[2][4];
  f32x4 oacc[2][4];
#pragma unroll
  for (int mi = 0; mi < 2; mi++) {
#pragma unroll
    for (int r = 0; r < 4; r++) { mst[mi][r] = NEG_BIG; lst[mi][r] = 0.f; }
#pragma unroll
    for (int nd = 0; nd < 4; nd++) oacc[mi][nd] = (f32x4)0.0f;
  }

  const int ntiles = qt * 2 + 2;
  for (int kt = 0; kt < ntiles; kt++) {
    const int kvb = kt * 64;
    f32x4 kacc[4], vacc[4];
#pragma unroll
    for (int nd = 0; nd < 4; nd++) { kacc[nd] = (f32x4)0.0f; vacc[nd] = (f32x4)0.0f; }
    for (int k0 = 0; k0 < 1024; k0 += 32) {
      __syncthreads();
      {
        int r = tid >> 2, kk = (tid & 3) << 3;
        *(uint4v*)&xkv[r * 32 + kk] = ld8bf(&xp[(size_t)(kvb + r) * 1024 + k0 + kk]);
        *(uint4v*)&wks[r * 32 + kk] = ld8bf(&wkp[(size_t)r * 1024 + k0 + kk]);
        *(uint4v*)&wvs[r * 32 + kk] = ld8bf(&wvp[(size_t)r * 1024 + k0 + kk]);
      }
      __syncthreads();
      short8 af = *(const short8*)&xkv[(w * 16 + lrow) * 32 + lk];
#pragma unroll
      for (int nd = 0; nd < 4; nd++) {
        short8 bk = *(const short8*)&wks[(nd * 16 + lrow) * 32 + lk];
        short8 bv = *(const short8*)&wvs[(nd * 16 + lrow) * 32 + lk];
        kacc[nd] = MFMA_BF16(af, bk, kacc[nd]);
        vacc[nd] = MFMA_BF16(af, bv, vacc[nd]);
      }
    }
#pragma unroll
    for (int nd = 0; nd < 4; nd++)
#pragma unroll
      for (int r = 0; r < 4; r++) {
        Ks[(w * 16 + lq + r) * 72 + nd * 16 + lrow] = f2bf(kacc[nd][r]);
        Vt[(nd * 16 + lrow) * 72 + w * 16 + lq + r] = f2bf(vacc[nd][r]);
      }
    __syncthreads();

    f32x4 s[2][4];
#pragma unroll
    for (int mi = 0; mi < 2; mi++)
#pragma unroll
      for (int nt = 0; nt < 4; nt++) {
        f32x4 a = (f32x4)0.0f;
#pragma unroll
        for (int ks = 0; ks < 2; ks++) {
          short8 kf = *(const short8*)&Ks[(nt * 16 + lrow) * 72 + ks * 32 + lk];
          a = MFMA_BF16(qf[mi][ks], kf, a);
        }
        s[mi][nt] = a;
      }

#pragma unroll
    for (int mi = 0; mi < 2; mi++) {
      int rowb = qb + w * 32 + mi * 16 + lq;
      float corr[4], lt[4];
#pragma unroll
      for (int r = 0; r < 4; r++) {
        float mx = NEG_BIG;
#pragma unroll
        for (int nt = 0; nt < 4; nt++) {
          int col = kvb + nt * 16 + lrow;
          float sv = s[mi][nt][r];
          if (col > rowb + r) sv = NEG_BIG;
          s[mi][nt][r] = sv;
          mx = fmaxf(mx, sv);
        }
#pragma unroll
        for (int off = 8; off >= 1; off >>= 1)
          mx = fmaxf(mx, __shfl_xor(mx, off));
        float mn = fmaxf(mst[mi][r], mx);
        corr[r] = __expf(mst[mi][r] - mn);
        mst[mi][r] = mn;
        float ls = 0.f;
#pragma unroll
        for (int nt = 0; nt < 4; nt++) {
          float p = __expf(s[mi][nt][r] - mn);
          s[mi][nt][r] = p;
          ls += p;
        }
#pragma unroll
        for (int off = 8; off >= 1; off >>= 1) ls += __shfl_xor(ls, off);
        lt[r] = ls;
      }
#pragma unroll
      for (int r = 0; r < 4; r++) {
        lst[mi][r] = corr[r] * lst[mi][r] + lt[r];
#pragma unroll
        for (int nd = 0; nd < 4; nd++) oacc[mi][nd][r] *= corr[r];
#pragma unroll
        for (int nt = 0; nt < 4; nt++)
          Ps[(w * 32 + mi * 16 + lq + r) * 72 + nt * 16 + lrow] =
              f2bf(s[mi][nt][r]);
      }
    }

#pragma unroll
    for (int ks = 0; ks < 2; ks++) {
      short8 vf[4];
#pragma unroll
      for (int nd = 0; nd < 4; nd++)
        vf[nd] = *(const short8*)&Vt[(nd * 16 + lrow) * 72 + ks * 32 + lk];
#pragma unroll
      for (int mi = 0; mi < 2; mi++) {
        short8 pf =
            *(const short8*)&Ps[(w * 32 + mi * 16 + lrow) * 72 + ks * 32 + lk];
#pragma unroll
        for (int nd = 0; nd < 4; nd++)
          oacc[mi][nd] = MFMA_BF16(pf, vf[nd], oacc[mi][nd]);
      }
    }
  }

#pragma unroll
  for (int mi = 0; mi < 2; mi++)
#pragma unroll
    for (int r = 0; r < 4; r++) {
      int t = qb + w * 32 + mi * 16 + lq + r;
      float inv = 1.f / lst[mi][r];
#pragma unroll
      for (int nd = 0; nd < 4; nd++) {
        int dd = nd * 16 + lrow;
        Og[((size_t)(b * T_SEQ + t)) * DMODEL + h * DHEAD + dd] =
            oacc[mi][nd][r] * inv;
      }
    }
}

__global__ __launch_bounds__(256) void oproj_inplace(float* __restrict__ IO,
                                                     const float* __restrict__ Wo) {
  __shared__ u16 Os[16 * 1024];
  __shared__ u16 Bs[128 * 32];
  const int tid = threadIdx.x, lane = tid & 63, w = tid >> 6;
  const int lrow = lane & 15;
  const int lk = (lane >> 4) << 3;
  const int lq = (lane >> 4) << 2;
  const int mBase = blockIdx.x * 16;

#pragma unroll
  for (int i = 0; i < 8; i++) {
    int c = i * 256 + tid;
    int row = c >> 7, kb = c & 127;
    *(uint4v*)&Os[row * 1024 + ((kb ^ (row & 7)) << 3)] =
        ld8bf(&IO[(size_t)(mBase + row) * 1024 + (kb << 3)]);
  }
  __syncthreads();

  for (int nt = 0; nt < 8; nt++) {
    f32x4 acc[2];
    acc[0] = (f32x4)0.0f;
    acc[1] = (f32x4)0.0f;
    for (int k0 = 0; k0 < 1024; k0 += 32) {
      __syncthreads();
#pragma unroll
      for (int i = 0; i < 2; i++) {
        int c = i * 256 + tid;
        int r = c >> 2, kk = (c & 3) << 3;
        *(uint4v*)&Bs[r * 32 + kk] =
            ld8bf(&Wo[(size_t)(nt * 128 + r) * 1024 + k0 + kk]);
      }
      __syncthreads();
      short8 af = *(const short8*)
          &Os[lrow * 1024 + ((((k0 + lk) >> 3) ^ (lrow & 7)) << 3)];
#pragma unroll
      for (int ni = 0; ni < 2; ni++) {
        short8 bf = *(const short8*)&Bs[(w * 32 + ni * 16 + lrow) * 32 + lk];
        acc[ni] = MFMA_BF16(af, bf, acc[ni]);
      }
    }
#pragma unroll
    for (int ni = 0; ni < 2; ni++)
#pragma unroll
      for (int r = 0; r < 4; r++)
        IO[(size_t)(mBase + lq + r) * 1024 + nt * 128 + w * 32 + ni * 16 +
           lrow] = acc[ni][r];
  }
}

// ---------------------------------------------------------------- launch
extern "C" void kernel_launch(void* const* d_in, const int* in_sizes, int n_in,
                              void* d_out, int out_size, void* d_ws,
                              size_t ws_size, hipStream_t stream) {
  const float* x = (const float*)d_in[0];
  const float* Wq = (const float*)d_in[1];
  const float* Wk = (const float*)d_in[2];
  const float* Wv = (const float*)d_in[3];
  const float* Wo = (const float*)d_in[4];
  float* out = (float*)d_out;

  const size_t NEED = 3u * 4194304u * sizeof(u16);  // K + V + O bf16 = 24 MB
  if (ws_size >= NEED) {
    u16* K = (u16*)d_ws;
    u16* V = K + 4194304;
    u16* O = V + 4194304;
    gemm_kv<<<dim3(32, 8, 2), 256, 0, stream>>>(x, Wk, Wv, K, V);
    attn_fq<<<dim3(16, 32), 256, 0, stream>>>(x, Wq, K, V, O);
    gemm_out<<<dim3(32, 8), 256, 0, stream>>>(O, Wo, out);
  } else {
    attn_fused<<<dim3(16, 32), 256, 0, stream>>>(x, Wq, Wk, Wv, out);
    oproj_inplace<<<dim3(256), 256, 0, stream>>>(out, Wo);
  }
}

// Round 7
// 273.292 us; speedup vs baseline: 4.5947x; 1.1761x over previous
//
#include <hip/hip_runtime.h>
#include <hip/hip_bf16.h>

typedef __attribute__((ext_vector_type(8))) short short8;
typedef __attribute__((ext_vector_type(4))) float f32x4;
typedef __attribute__((ext_vector_type(2))) unsigned int uint2v;
typedef __attribute__((ext_vector_type(4))) unsigned int uint4v;
typedef unsigned short u16;

#define MFMA_BF16(a, b, c) __builtin_amdgcn_mfma_f32_16x16x32_bf16(a, b, c, 0, 0, 0)

#define T_SEQ 2048
#define DMODEL 1024
#define NHEADS 16
#define DHEAD 64
#define NEG_BIG (-30000.0f)

__device__ __forceinline__ unsigned bfr(unsigned u) {
  return (u + 0x7fffu + ((u >> 16) & 1u)) >> 16;
}
__device__ __forceinline__ uint4v ld8bf(const float* __restrict__ p) {
  const uint4v a = *(const uint4v*)p;
  const uint4v b = *(const uint4v*)(p + 4);
  uint4v r;
  r[0] = bfr(a[0]) | (bfr(a[1]) << 16);
  r[1] = bfr(a[2]) | (bfr(a[3]) << 16);
  r[2] = bfr(b[0]) | (bfr(b[1]) << 16);
  r[3] = bfr(b[2]) | (bfr(b[3]) << 16);
  return r;
}
__device__ __forceinline__ u16 f2bf(float f) {
  unsigned u = __float_as_uint(f);
  u += 0x7fffu + ((u >> 16) & 1u);
  return (u16)(u >> 16);
}

// ================================================================ TIER 48
// ---------------------------------------------------------------- cvt fp32->bf16
// x: 4M elems -> blocks [0,2048); each W: 1M -> 512 blocks each.
__global__ __launch_bounds__(256) void cvt_all(
    const float* __restrict__ x, const float* __restrict__ wq,
    const float* __restrict__ wk, const float* __restrict__ wv,
    const float* __restrict__ wo, u16* __restrict__ xh, u16* __restrict__ wqh,
    u16* __restrict__ wkh, u16* __restrict__ wvh, u16* __restrict__ woh) {
  int bi = blockIdx.x;
  const float* s;
  u16* d;
  size_t base;
  if (bi < 2048) {
    s = x; d = xh; base = (size_t)bi * 2048;
  } else {
    int k = (bi - 2048) >> 9;
    int r = (bi - 2048) & 511;
    s = (k == 0) ? wq : (k == 1) ? wk : (k == 2) ? wv : wo;
    d = (k == 0) ? wqh : (k == 1) ? wkh : (k == 2) ? wvh : woh;
    base = (size_t)r * 2048;
  }
  size_t i = base + (size_t)threadIdx.x * 8;
  *(uint4v*)&d[i] = ld8bf(&s[i]);
}

// ---------------------------------------------------------------- QKV proj (bf16)
// grid (32,8,3): z=0 Q (pre-scaled 1/8), z=1 K, z=2 V. Scatter (b,h,t,64) bf16.
__global__ __launch_bounds__(256) void gemm_qkv(
    const u16* __restrict__ X, const u16* __restrict__ Wq,
    const u16* __restrict__ Wk, const u16* __restrict__ Wv,
    u16* __restrict__ Qo, u16* __restrict__ Ko, u16* __restrict__ Vo) {
  __shared__ u16 As[128 * 32];
  __shared__ u16 Bs[128 * 32];
  const int tid = threadIdx.x, lane = tid & 63, w = tid >> 6;
  const int wm = (w >> 1) * 64, wn = (w & 1) * 64;
  const int lrow = lane & 15;
  const int lk = (lane >> 4) << 3;
  const int lq = (lane >> 4) << 2;
  const int mBase = blockIdx.x * 128, nBase = blockIdx.y * 128;
  const u16* Bt = (blockIdx.z == 0) ? Wq : (blockIdx.z == 1) ? Wk : Wv;
  u16* D = (blockIdx.z == 0) ? Qo : (blockIdx.z == 1) ? Ko : Vo;
  const float scale = (blockIdx.z == 0) ? 0.125f : 1.0f;

  f32x4 acc[4][4];
#pragma unroll
  for (int mi = 0; mi < 4; mi++)
#pragma unroll
    for (int ni = 0; ni < 4; ni++) acc[mi][ni] = (f32x4)0.0f;

  for (int k0 = 0; k0 < 1024; k0 += 32) {
    __syncthreads();
#pragma unroll
    for (int i = 0; i < 2; i++) {
      int c = i * 256 + tid;
      int r = c >> 2, kk = (c & 3) << 3;
      *(uint4v*)&As[c * 8] = *(const uint4v*)&X[(size_t)(mBase + r) * 1024 + k0 + kk];
      *(uint4v*)&Bs[c * 8] = *(const uint4v*)&Bt[(size_t)(nBase + r) * 1024 + k0 + kk];
    }
    __syncthreads();
    short8 af[4], bf[4];
#pragma unroll
    for (int mi = 0; mi < 4; mi++)
      af[mi] = *(const short8*)&As[(wm + mi * 16 + lrow) * 32 + lk];
#pragma unroll
    for (int ni = 0; ni < 4; ni++)
      bf[ni] = *(const short8*)&Bs[(wn + ni * 16 + lrow) * 32 + lk];
#pragma unroll
    for (int mi = 0; mi < 4; mi++)
#pragma unroll
      for (int ni = 0; ni < 4; ni++)
        acc[mi][ni] = MFMA_BF16(af[mi], bf[ni], acc[mi][ni]);
  }
#pragma unroll
  for (int mi = 0; mi < 4; mi++)
#pragma unroll
    for (int r = 0; r < 4; r++) {
      int m = mBase + wm + mi * 16 + lq + r;
      int b = m >> 11, t = m & 2047;
#pragma unroll
      for (int ni = 0; ni < 4; ni++) {
        int n = nBase + wn + ni * 16 + lrow;
        int h = n >> 6, dd = n & 63;
        D[(((size_t)(b * NHEADS + h)) * T_SEQ + t) * DHEAD + dd] =
            f2bf(acc[mi][ni][r] * scale);
      }
    }
}

// ---------------------------------------------------------------- attention
// grid (16,32), 512 thr = 8 waves; wave owns 16 q-rows. Q/K/V from ws bf16.
// Ps aliases Qs after q-fragments are loaded -> 36.9 KB LDS.
__global__ __launch_bounds__(512, 4) void attn_pre(
    const u16* __restrict__ Qg, const u16* __restrict__ Kg,
    const u16* __restrict__ Vg, u16* __restrict__ Ob) {
  __shared__ u16 smem[18432];  // 36864 B
  u16* Qs = smem;              // 128*72; reused as Ps inside kv loop
  u16* Ps = smem;
  u16* Ks = smem + 9216;       // 64*72
  u16* Vt = smem + 13824;      // 64*72 (V transposed Vt[d][kv])

  const int tid = threadIdx.x;
  const int w = tid >> 6, lane = tid & 63;
  const int lrow = lane & 15;
  const int lk = (lane >> 4) << 3;
  const int lq = (lane >> 4) << 2;

  const int qt = gridDim.x - 1 - blockIdx.x;  // heavy blocks first
  const int qb = qt * 128;
  const int bh = blockIdx.y;
  const int b = bh >> 4, h = bh & 15;
  const u16* Qp = Qg + (size_t)bh * T_SEQ * DHEAD;
  const u16* Kp = Kg + (size_t)bh * T_SEQ * DHEAD;
  const u16* Vp = Vg + (size_t)bh * T_SEQ * DHEAD;

  // stage Q tile (pre-scaled by 1/8 in gemm_qkv)
#pragma unroll
  for (int i = 0; i < 2; i++) {
    int c = i * 512 + tid;
    int r = c >> 3, kk = (c & 7) << 3;
    *(uint4v*)&Qs[r * 72 + kk] = *(const uint4v*)&Qp[(size_t)(qb + r) * DHEAD + kk];
  }
  __syncthreads();
  short8 qf[2];
#pragma unroll
  for (int ks = 0; ks < 2; ks++)
    qf[ks] = *(const short8*)&Qs[(w * 16 + lrow) * 72 + ks * 32 + lk];

  float mst[4], lst[4];
  f32x4 oacc[4];
#pragma unroll
  for (int r = 0; r < 4; r++) { mst[r] = NEG_BIG; lst[r] = 0.f; }
#pragma unroll
  for (int nd = 0; nd < 4; nd++) oacc[nd] = (f32x4)0.0f;

  const int ntiles = qt * 2 + 2;
  for (int kt = 0; kt < ntiles; kt++) {
    const int kvb = kt * 64;
    __syncthreads();  // prior readers of Ks/Vt/Ps done; qf reads done (pre-loop)
    {  // stage K (64x64): 512 chunks of 8
      int r = tid >> 3, kk = (tid & 7) << 3;
      *(uint4v*)&Ks[r * 72 + kk] = *(const uint4v*)&Kp[(size_t)(kvb + r) * DHEAD + kk];
    }
#pragma unroll
    for (int i = 0; i < 2; i++) {  // stage V transposed
      int q = i * 512 + tid;
      int r = q >> 4, cc = (q & 15) << 2;
      uint2v v = *(const uint2v*)&Vp[(size_t)(kvb + r) * DHEAD + cc];
      Vt[(cc + 0) * 72 + r] = (u16)(v[0] & 0xffffu);
      Vt[(cc + 1) * 72 + r] = (u16)(v[0] >> 16);
      Vt[(cc + 2) * 72 + r] = (u16)(v[1] & 0xffffu);
      Vt[(cc + 3) * 72 + r] = (u16)(v[1] >> 16);
    }
    __syncthreads();

    // S = Q K^T (wave: 16 x 64)
    f32x4 s[4];
#pragma unroll
    for (int nt = 0; nt < 4; nt++) {
      f32x4 a = (f32x4)0.0f;
#pragma unroll
      for (int ks = 0; ks < 2; ks++) {
        short8 kf = *(const short8*)&Ks[(nt * 16 + lrow) * 72 + ks * 32 + lk];
        a = MFMA_BF16(qf[ks], kf, a);
      }
      s[nt] = a;
    }

    // online softmax
    const int rowb = qb + w * 16 + lq;
    float corr[4], lt[4];
#pragma unroll
    for (int r = 0; r < 4; r++) {
      float mx = NEG_BIG;
#pragma unroll
      for (int nt = 0; nt < 4; nt++) {
        int col = kvb + nt * 16 + lrow;
        float sv = s[nt][r];
        if (col > rowb + r) sv = NEG_BIG;
        s[nt][r] = sv;
        mx = fmaxf(mx, sv);
      }
#pragma unroll
      for (int off = 8; off >= 1; off >>= 1) mx = fmaxf(mx, __shfl_xor(mx, off));
      float mn = fmaxf(mst[r], mx);
      corr[r] = __expf(mst[r] - mn);
      mst[r] = mn;
      float ls = 0.f;
#pragma unroll
      for (int nt = 0; nt < 4; nt++) {
        float p = __expf(s[nt][r] - mn);
        s[nt][r] = p;
        ls += p;
      }
#pragma unroll
      for (int off = 8; off >= 1; off >>= 1) ls += __shfl_xor(ls, off);
      lt[r] = ls;
    }
#pragma unroll
    for (int r = 0; r < 4; r++) {
      lst[r] = corr[r] * lst[r] + lt[r];
#pragma unroll
      for (int nd = 0; nd < 4; nd++) oacc[nd][r] *= corr[r];
#pragma unroll
      for (int nt = 0; nt < 4; nt++)
        Ps[(w * 16 + lq + r) * 72 + nt * 16 + lrow] = f2bf(s[nt][r]);
    }

    // O += P @ V (P wave-private rows; same-wave LDS ordering)
#pragma unroll
    for (int ks = 0; ks < 2; ks++) {
      short8 vf[4];
#pragma unroll
      for (int nd = 0; nd < 4; nd++)
        vf[nd] = *(const short8*)&Vt[(nd * 16 + lrow) * 72 + ks * 32 + lk];
      short8 pf = *(const short8*)&Ps[(w * 16 + lrow) * 72 + ks * 32 + lk];
#pragma unroll
      for (int nd = 0; nd < 4; nd++) oacc[nd] = MFMA_BF16(pf, vf[nd], oacc[nd]);
    }
  }

  // normalize + write O bf16 (b, t, h*64+d)
#pragma unroll
  for (int r = 0; r < 4; r++) {
    int t = qb + w * 16 + lq + r;
    float inv = 1.f / lst[r];
#pragma unroll
    for (int nd = 0; nd < 4; nd++)
      Ob[((size_t)(b * T_SEQ + t)) * DMODEL + h * DHEAD + nd * 16 + lrow] =
          f2bf(oacc[nd][r] * inv);
  }
}

// ---------------------------------------------------------------- out proj (bf16 W)
__global__ __launch_bounds__(256) void gemm_out_bf(const u16* __restrict__ O,
                                                   const u16* __restrict__ Wo,
                                                   float* __restrict__ Out) {
  __shared__ u16 As[128 * 32];
  __shared__ u16 Bs[128 * 32];
  const int tid = threadIdx.x, lane = tid & 63, w = tid >> 6;
  const int wm = (w >> 1) * 64, wn = (w & 1) * 64;
  const int lrow = lane & 15;
  const int lk = (lane >> 4) << 3;
  const int lq = (lane >> 4) << 2;
  const int mBase = blockIdx.x * 128, nBase = blockIdx.y * 128;

  f32x4 acc[4][4];
#pragma unroll
  for (int mi = 0; mi < 4; mi++)
#pragma unroll
    for (int ni = 0; ni < 4; ni++) acc[mi][ni] = (f32x4)0.0f;

  for (int k0 = 0; k0 < 1024; k0 += 32) {
    __syncthreads();
#pragma unroll
    for (int i = 0; i < 2; i++) {
      int c = i * 256 + tid;
      int r = c >> 2, kk = (c & 3) << 3;
      *(uint4v*)&As[c * 8] = *(const uint4v*)&O[(size_t)(mBase + r) * 1024 + k0 + kk];
      *(uint4v*)&Bs[c * 8] = *(const uint4v*)&Wo[(size_t)(nBase + r) * 1024 + k0 + kk];
    }
    __syncthreads();
    short8 af[4], bf[4];
#pragma unroll
    for (int mi = 0; mi < 4; mi++)
      af[mi] = *(const short8*)&As[(wm + mi * 16 + lrow) * 32 + lk];
#pragma unroll
    for (int ni = 0; ni < 4; ni++)
      bf[ni] = *(const short8*)&Bs[(wn + ni * 16 + lrow) * 32 + lk];
#pragma unroll
    for (int mi = 0; mi < 4; mi++)
#pragma unroll
      for (int ni = 0; ni < 4; ni++)
        acc[mi][ni] = MFMA_BF16(af[mi], bf[ni], acc[mi][ni]);
  }
#pragma unroll
  for (int mi = 0; mi < 4; mi++)
#pragma unroll
    for (int r = 0; r < 4; r++) {
      int m = mBase + wm + mi * 16 + lq + r;
#pragma unroll
      for (int ni = 0; ni < 4; ni++)
        Out[(size_t)m * DMODEL + nBase + wn + ni * 16 + lrow] = acc[mi][ni][r];
    }
}

// ================================================================ TIER 24
// (round-6 validated pipeline, verbatim)
__global__ __launch_bounds__(256) void gemm_kv(
    const float* __restrict__ X, const float* __restrict__ Wk,
    const float* __restrict__ Wv, u16* __restrict__ Ko, u16* __restrict__ Vo) {
  __shared__ u16 As[128 * 32];
  __shared__ u16 Bs[128 * 32];
  const int tid = threadIdx.x, lane = tid & 63, w = tid >> 6;
  const int wm = (w >> 1) * 64, wn = (w & 1) * 64;
  const int lrow = lane & 15;
  const int lk = (lane >> 4) << 3;
  const int lq = (lane >> 4) << 2;
  const int mBase = blockIdx.x * 128, nBase = blockIdx.y * 128;
  const float* Bt = (blockIdx.z == 0) ? Wk : Wv;
  u16* D = (blockIdx.z == 0) ? Ko : Vo;

  f32x4 acc[4][4];
#pragma unroll
  for (int mi = 0; mi < 4; mi++)
#pragma unroll
    for (int ni = 0; ni < 4; ni++) acc[mi][ni] = (f32x4)0.0f;

  for (int k0 = 0; k0 < 1024; k0 += 32) {
    __syncthreads();
#pragma unroll
    for (int i = 0; i < 2; i++) {
      int c = i * 256 + tid;
      int r = c >> 2, kk = (c & 3) << 3;
      *(uint4v*)&As[c * 8] = ld8bf(&X[(size_t)(mBase + r) * 1024 + k0 + kk]);
      *(uint4v*)&Bs[c * 8] = ld8bf(&Bt[(size_t)(nBase + r) * 1024 + k0 + kk]);
    }
    __syncthreads();
    short8 af[4], bf[4];
#pragma unroll
    for (int mi = 0; mi < 4; mi++)
      af[mi] = *(const short8*)&As[(wm + mi * 16 + lrow) * 32 + lk];
#pragma unroll
    for (int ni = 0; ni < 4; ni++)
      bf[ni] = *(const short8*)&Bs[(wn + ni * 16 + lrow) * 32 + lk];
#pragma unroll
    for (int mi = 0; mi < 4; mi++)
#pragma unroll
      for (int ni = 0; ni < 4; ni++)
        acc[mi][ni] = MFMA_BF16(af[mi], bf[ni], acc[mi][ni]);
  }
#pragma unroll
  for (int mi = 0; mi < 4; mi++)
#pragma unroll
    for (int r = 0; r < 4; r++) {
      int m = mBase + wm + mi * 16 + lq + r;
      int b = m >> 11, t = m & 2047;
#pragma unroll
      for (int ni = 0; ni < 4; ni++) {
        int n = nBase + wn + ni * 16 + lrow;
        int h = n >> 6, dd = n & 63;
        D[(((size_t)(b * NHEADS + h)) * T_SEQ + t) * DHEAD + dd] =
            f2bf(acc[mi][ni][r]);
      }
    }
}

__global__ __launch_bounds__(256) void attn_fq(
    const float* __restrict__ X, const float* __restrict__ Wq,
    const u16* __restrict__ Kg, const u16* __restrict__ Vg,
    u16* __restrict__ Ob) {
  __shared__ u16 smem[27648];
  u16* Qs = smem;
  u16* Ks = smem + 9216;
  u16* Vt = smem + 13824;
  u16* Ps = smem + 18432;
  u16* xs = Ks;
  u16* wqs = Vt;

  const int tid = threadIdx.x;
  const int w = tid >> 6, lane = tid & 63;
  const int lrow = lane & 15;
  const int lk = (lane >> 4) << 3;
  const int lq = (lane >> 4) << 2;

  const int qt = gridDim.x - 1 - blockIdx.x;
  const int qb = qt * 128;
  const int bh = blockIdx.y;
  const int b = bh >> 4, h = bh & 15;
  const float* xp = X + (size_t)b * T_SEQ * DMODEL;
  const float* wqp = Wq + (size_t)h * DHEAD * DMODEL;
  const u16* Kp = Kg + (size_t)bh * T_SEQ * DHEAD;
  const u16* Vp = Vg + (size_t)bh * T_SEQ * DHEAD;

  f32x4 qacc[2][4];
#pragma unroll
  for (int mi = 0; mi < 2; mi++)
#pragma unroll
    for (int nd = 0; nd < 4; nd++) qacc[mi][nd] = (f32x4)0.0f;

  for (int k0 = 0; k0 < 1024; k0 += 32) {
    __syncthreads();
#pragma unroll
    for (int i = 0; i < 2; i++) {
      int c = i * 256 + tid;
      int r = c >> 2, kk = (c & 3) << 3;
      *(uint4v*)&xs[r * 32 + kk] = ld8bf(&xp[(size_t)(qb + r) * 1024 + k0 + kk]);
    }
    {
      int r = tid >> 2, kk = (tid & 3) << 3;
      *(uint4v*)&wqs[r * 32 + kk] = ld8bf(&wqp[(size_t)r * 1024 + k0 + kk]);
    }
    __syncthreads();
    short8 bfrag[4];
#pragma unroll
    for (int nd = 0; nd < 4; nd++)
      bfrag[nd] = *(const short8*)&wqs[(nd * 16 + lrow) * 32 + lk];
#pragma unroll
    for (int mi = 0; mi < 2; mi++) {
      short8 af = *(const short8*)&xs[(w * 32 + mi * 16 + lrow) * 32 + lk];
#pragma unroll
      for (int nd = 0; nd < 4; nd++)
        qacc[mi][nd] = MFMA_BF16(af, bfrag[nd], qacc[mi][nd]);
    }
  }
  __syncthreads();
#pragma unroll
  for (int mi = 0; mi < 2; mi++)
#pragma unroll
    for (int r = 0; r < 4; r++)
#pragma unroll
      for (int nd = 0; nd < 4; nd++)
        Qs[(w * 32 + mi * 16 + lq + r) * 72 + nd * 16 + lrow] =
            f2bf(qacc[mi][nd][r] * 0.125f);
  short8 qf[2][2];
#pragma unroll
  for (int mi = 0; mi < 2; mi++)
#pragma unroll
    for (int ks = 0; ks < 2; ks++)
      qf[mi][ks] =
          *(const short8*)&Qs[(w * 32 + mi * 16 + lrow) * 72 + ks * 32 + lk];

  float mst[2][4], lst[2][4];
  f32x4 oacc[2][4];
#pragma unroll
  for (int mi = 0; mi < 2; mi++) {
#pragma unroll
    for (int r = 0; r < 4; r++) { mst[mi][r] = NEG_BIG; lst[mi][r] = 0.f; }
#pragma unroll
    for (int nd = 0; nd < 4; nd++) oacc[mi][nd] = (f32x4)0.0f;
  }

  const int ntiles = qt * 2 + 2;
  for (int kt = 0; kt < ntiles; kt++) {
    const int kvb = kt * 64;
    __syncthreads();
#pragma unroll
    for (int i = 0; i < 2; i++) {
      int c = i * 256 + tid;
      int r = c >> 3, kk = (c & 7) << 3;
      *(uint4v*)&Ks[r * 72 + kk] =
          *(const uint4v*)&Kp[(size_t)(kvb + r) * DHEAD + kk];
    }
#pragma unroll
    for (int i = 0; i < 4; i++) {
      int q = i * 256 + tid;
      int r = q >> 4, cc = (q & 15) << 2;
      uint2v v = *(const uint2v*)&Vp[(size_t)(kvb + r) * DHEAD + cc];
      Vt[(cc + 0) * 72 + r] = (u16)(v[0] & 0xffffu);
      Vt[(cc + 1) * 72 + r] = (u16)(v[0] >> 16);
      Vt[(cc + 2) * 72 + r] = (u16)(v[1] & 0xffffu);
      Vt[(cc + 3) * 72 + r] = (u16)(v[1] >> 16);
    }
    __syncthreads();

    f32x4 s[2][4];
#pragma unroll
    for (int mi = 0; mi < 2; mi++)
#pragma unroll
      for (int nt = 0; nt < 4; nt++) {
        f32x4 a = (f32x4)0.0f;
#pragma unroll
        for (int ks = 0; ks < 2; ks++) {
          short8 kf = *(const short8*)&Ks[(nt * 16 + lrow) * 72 + ks * 32 + lk];
          a = MFMA_BF16(qf[mi][ks], kf, a);
        }
        s[mi][nt] = a;
      }

#pragma unroll
    for (int mi = 0; mi < 2; mi++) {
      int rowb = qb + w * 32 + mi * 16 + lq;
      float corr[4], lt[4];
#pragma unroll
      for (int r = 0; r < 4; r++) {
        float mx = NEG_BIG;
#pragma unroll
        for (int nt = 0; nt < 4; nt++) {
          int col = kvb + nt * 16 + lrow;
          float sv = s[mi][nt][r];
          if (col > rowb + r) sv = NEG_BIG;
          s[mi][nt][r] = sv;
          mx = fmaxf(mx, sv);
        }
#pragma unroll
        for (int off = 8; off >= 1; off >>= 1)
          mx = fmaxf(mx, __shfl_xor(mx, off));
        float mn = fmaxf(mst[mi][r], mx);
        corr[r] = __expf(mst[mi][r] - mn);
        mst[mi][r] = mn;
        float ls = 0.f;
#pragma unroll
        for (int nt = 0; nt < 4; nt++) {
          float p = __expf(s[mi][nt][r] - mn);
          s[mi][nt][r] = p;
          ls += p;
        }
#pragma unroll
        for (int off = 8; off >= 1; off >>= 1) ls += __shfl_xor(ls, off);
        lt[r] = ls;
      }
#pragma unroll
      for (int r = 0; r < 4; r++) {
        lst[mi][r] = corr[r] * lst[mi][r] + lt[r];
#pragma unroll
        for (int nd = 0; nd < 4; nd++) oacc[mi][nd][r] *= corr[r];
#pragma unroll
        for (int nt = 0; nt < 4; nt++)
          Ps[(w * 32 + mi * 16 + lq + r) * 72 + nt * 16 + lrow] =
              f2bf(s[mi][nt][r]);
      }
    }

#pragma unroll
    for (int ks = 0; ks < 2; ks++) {
      short8 vf[4];
#pragma unroll
      for (int nd = 0; nd < 4; nd++)
        vf[nd] = *(const short8*)&Vt[(nd * 16 + lrow) * 72 + ks * 32 + lk];
#pragma unroll
      for (int mi = 0; mi < 2; mi++) {
        short8 pf =
            *(const short8*)&Ps[(w * 32 + mi * 16 + lrow) * 72 + ks * 32 + lk];
#pragma unroll
        for (int nd = 0; nd < 4; nd++)
          oacc[mi][nd] = MFMA_BF16(pf, vf[nd], oacc[mi][nd]);
      }
    }
  }

#pragma unroll
  for (int mi = 0; mi < 2; mi++)
#pragma unroll
    for (int r = 0; r < 4; r++) {
      int t = qb + w * 32 + mi * 16 + lq + r;
      float inv = 1.f / lst[mi][r];
#pragma unroll
      for (int nd = 0; nd < 4; nd++) {
        int dd = nd * 16 + lrow;
        Ob[((size_t)(b * T_SEQ + t)) * DMODEL + h * DHEAD + dd] =
            f2bf(oacc[mi][nd][r] * inv);
      }
    }
}

__global__ __launch_bounds__(256) void gemm_out_w32(const u16* __restrict__ O,
                                                    const float* __restrict__ Wo,
                                                    float* __restrict__ Out) {
  __shared__ u16 As[128 * 32];
  __shared__ u16 Bs[128 * 32];
  const int tid = threadIdx.x, lane = tid & 63, w = tid >> 6;
  const int wm = (w >> 1) * 64, wn = (w & 1) * 64;
  const int lrow = lane & 15;
  const int lk = (lane >> 4) << 3;
  const int lq = (lane >> 4) << 2;
  const int mBase = blockIdx.x * 128, nBase = blockIdx.y * 128;

  f32x4 acc[4][4];
#pragma unroll
  for (int mi = 0; mi < 4; mi++)
#pragma unroll
    for (int ni = 0; ni < 4; ni++) acc[mi][ni] = (f32x4)0.0f;

  for (int k0 = 0; k0 < 1024; k0 += 32) {
    __syncthreads();
#pragma unroll
    for (int i = 0; i < 2; i++) {
      int c = i * 256 + tid;
      int r = c >> 2, kk = (c & 3) << 3;
      *(uint4v*)&As[c * 8] =
          *(const uint4v*)&O[(size_t)(mBase + r) * 1024 + k0 + kk];
      *(uint4v*)&Bs[c * 8] = ld8bf(&Wo[(size_t)(nBase + r) * 1024 + k0 + kk]);
    }
    __syncthreads();
    short8 af[4], bf[4];
#pragma unroll
    for (int mi = 0; mi < 4; mi++)
      af[mi] = *(const short8*)&As[(wm + mi * 16 + lrow) * 32 + lk];
#pragma unroll
    for (int ni = 0; ni < 4; ni++)
      bf[ni] = *(const short8*)&Bs[(wn + ni * 16 + lrow) * 32 + lk];
#pragma unroll
    for (int mi = 0; mi < 4; mi++)
#pragma unroll
      for (int ni = 0; ni < 4; ni++)
        acc[mi][ni] = MFMA_BF16(af[mi], bf[ni], acc[mi][ni]);
  }
#pragma unroll
  for (int mi = 0; mi < 4; mi++)
#pragma unroll
    for (int r = 0; r < 4; r++) {
      int m = mBase + wm + mi * 16 + lq + r;
#pragma unroll
      for (int ni = 0; ni < 4; ni++)
        Out[(size_t)m * DMODEL + nBase + wn + ni * 16 + lrow] = acc[mi][ni][r];
    }
}

// ---------------------------------------------------------------- launch
extern "C" void kernel_launch(void* const* d_in, const int* in_sizes, int n_in,
                              void* d_out, int out_size, void* d_ws,
                              size_t ws_size, hipStream_t stream) {
  const float* x = (const float*)d_in[0];
  const float* Wq = (const float*)d_in[1];
  const float* Wk = (const float*)d_in[2];
  const float* Wv = (const float*)d_in[3];
  const float* Wo = (const float*)d_in[4];
  float* out = (float*)d_out;

  const size_t NEED48 = 48u * 1024u * 1024u;
  const size_t NEED24 = 24u * 1024u * 1024u;
  if (ws_size >= NEED48) {
    u16* xh = (u16*)d_ws;            // 4M elems
    u16* wqh = xh + 4194304;         // 1M each
    u16* wkh = wqh + 1048576;
    u16* wvh = wkh + 1048576;
    u16* woh = wvh + 1048576;
    u16* Q = woh + 1048576;          // 4M each
    u16* K = Q + 4194304;
    u16* V = K + 4194304;
    u16* O = V + 4194304;
    cvt_all<<<dim3(4096), 256, 0, stream>>>(x, Wq, Wk, Wv, Wo, xh, wqh, wkh, wvh, woh);
    gemm_qkv<<<dim3(32, 8, 3), 256, 0, stream>>>(xh, wqh, wkh, wvh, Q, K, V);
    attn_pre<<<dim3(16, 32), 512, 0, stream>>>(Q, K, V, O);
    gemm_out_bf<<<dim3(32, 8), 256, 0, stream>>>(O, woh, out);
  } else {
    // proven >= 24 MB path (round 6)
    u16* K = (u16*)d_ws;
    u16* V = K + 4194304;
    u16* O = V + 4194304;
    (void)NEED24;
    gemm_kv<<<dim3(32, 8, 2), 256, 0, stream>>>(x, Wk, Wv, K, V);
    attn_fq<<<dim3(16, 32), 256, 0, stream>>>(x, Wq, K, V, O);
    gemm_out_w32<<<dim3(32, 8), 256, 0, stream>>>(O, Wo, out);
  }
}

// Round 8
// 208.672 us; speedup vs baseline: 6.0176x; 1.3097x over previous
//
#include <hip/hip_runtime.h>
#include <hip/hip_bf16.h>

typedef __attribute__((ext_vector_type(8))) short short8;
typedef __attribute__((ext_vector_type(4))) float f32x4;
typedef __attribute__((ext_vector_type(4))) unsigned int uint4v;
typedef unsigned short u16;

#define MFMA_BF16(a, b, c) __builtin_amdgcn_mfma_f32_16x16x32_bf16(a, b, c, 0, 0, 0)

#define T_SEQ 2048
#define DMODEL 1024
#define NHEADS 16
#define DHEAD 64
#define NEG_BIG (-30000.0f)

__device__ __forceinline__ unsigned bfr(unsigned u) {
  return (u + 0x7fffu + ((u >> 16) & 1u)) >> 16;
}
__device__ __forceinline__ uint4v ld8bf(const float* __restrict__ p) {
  const uint4v a = *(const uint4v*)p;
  const uint4v b = *(const uint4v*)(p + 4);
  uint4v r;
  r[0] = bfr(a[0]) | (bfr(a[1]) << 16);
  r[1] = bfr(a[2]) | (bfr(a[3]) << 16);
  r[2] = bfr(b[0]) | (bfr(b[1]) << 16);
  r[3] = bfr(b[2]) | (bfr(b[3]) << 16);
  return r;
}
__device__ __forceinline__ u16 f2bf(float f) {
  unsigned u = __float_as_uint(f);
  u += 0x7fffu + ((u >> 16) & 1u);
  return (u16)(u >> 16);
}

// 16-lane allreduce on the VALU pipe (DPP), groups = lanes with same (lane>>4).
// quad_perm butterflies within quads, then row_ror 4/8 combine the 4 quads.
__device__ __forceinline__ float dpp16_max(float x) {
  float t;
  t = __int_as_float(__builtin_amdgcn_update_dpp(0, __float_as_int(x), 0xB1, 0xF, 0xF, true));
  x = fmaxf(x, t);
  t = __int_as_float(__builtin_amdgcn_update_dpp(0, __float_as_int(x), 0x4E, 0xF, 0xF, true));
  x = fmaxf(x, t);
  t = __int_as_float(__builtin_amdgcn_update_dpp(0, __float_as_int(x), 0x124, 0xF, 0xF, true));
  x = fmaxf(x, t);
  t = __int_as_float(__builtin_amdgcn_update_dpp(0, __float_as_int(x), 0x128, 0xF, 0xF, true));
  x = fmaxf(x, t);
  return x;
}
__device__ __forceinline__ float dpp16_sum(float x) {
  float t;
  t = __int_as_float(__builtin_amdgcn_update_dpp(0, __float_as_int(x), 0xB1, 0xF, 0xF, true));
  x += t;
  t = __int_as_float(__builtin_amdgcn_update_dpp(0, __float_as_int(x), 0x4E, 0xF, 0xF, true));
  x += t;
  t = __int_as_float(__builtin_amdgcn_update_dpp(0, __float_as_int(x), 0x124, 0xF, 0xF, true));
  x += t;
  t = __int_as_float(__builtin_amdgcn_update_dpp(0, __float_as_int(x), 0x128, 0xF, 0xF, true));
  x += t;
  return x;
}

// ---------------------------------------------------------------- cvt fp32->bf16
__global__ __launch_bounds__(256) void cvt_all(
    const float* __restrict__ x, const float* __restrict__ wq,
    const float* __restrict__ wk, const float* __restrict__ wv,
    const float* __restrict__ wo, u16* __restrict__ xh, u16* __restrict__ wqh,
    u16* __restrict__ wkh, u16* __restrict__ wvh, u16* __restrict__ woh) {
  int bi = blockIdx.x;
  const float* s;
  u16* d;
  size_t base;
  if (bi < 2048) {
    s = x; d = xh; base = (size_t)bi * 2048;
  } else {
    int k = (bi - 2048) >> 9;
    int r = (bi - 2048) & 511;
    s = (k == 0) ? wq : (k == 1) ? wk : (k == 2) ? wv : wo;
    d = (k == 0) ? wqh : (k == 1) ? wkh : (k == 2) ? wvh : woh;
    base = (size_t)r * 2048;
  }
  size_t i = base + (size_t)threadIdx.x * 8;
  *(uint4v*)&d[i] = ld8bf(&s[i]);
}

// ---------------------------------------------------------------- QKV proj (bf16)
// grid (32,8,3): z=0 Q (pre-scaled 1/8), z=1 K, z=2 V. Scatter (b,h,t,64) bf16.
__global__ __launch_bounds__(256) void gemm_qkv(
    const u16* __restrict__ X, const u16* __restrict__ Wq,
    const u16* __restrict__ Wk, const u16* __restrict__ Wv,
    u16* __restrict__ Qo, u16* __restrict__ Ko, u16* __restrict__ Vo) {
  __shared__ u16 As[128 * 32];
  __shared__ u16 Bs[128 * 32];
  const int tid = threadIdx.x, lane = tid & 63, w = tid >> 6;
  const int wm = (w >> 1) * 64, wn = (w & 1) * 64;
  const int lrow = lane & 15;
  const int lk = (lane >> 4) << 3;
  const int lq = (lane >> 4) << 2;
  const int mBase = blockIdx.x * 128, nBase = blockIdx.y * 128;
  const u16* Bt = (blockIdx.z == 0) ? Wq : (blockIdx.z == 1) ? Wk : Wv;
  u16* D = (blockIdx.z == 0) ? Qo : (blockIdx.z == 1) ? Ko : Vo;
  const float scale = (blockIdx.z == 0) ? 0.125f : 1.0f;

  f32x4 acc[4][4];
#pragma unroll
  for (int mi = 0; mi < 4; mi++)
#pragma unroll
    for (int ni = 0; ni < 4; ni++) acc[mi][ni] = (f32x4)0.0f;

  for (int k0 = 0; k0 < 1024; k0 += 32) {
    __syncthreads();
#pragma unroll
    for (int i = 0; i < 2; i++) {
      int c = i * 256 + tid;
      int r = c >> 2, kk = (c & 3) << 3;
      *(uint4v*)&As[c * 8] = *(const uint4v*)&X[(size_t)(mBase + r) * 1024 + k0 + kk];
      *(uint4v*)&Bs[c * 8] = *(const uint4v*)&Bt[(size_t)(nBase + r) * 1024 + k0 + kk];
    }
    __syncthreads();
    short8 af[4], bf[4];
#pragma unroll
    for (int mi = 0; mi < 4; mi++)
      af[mi] = *(const short8*)&As[(wm + mi * 16 + lrow) * 32 + lk];
#pragma unroll
    for (int ni = 0; ni < 4; ni++)
      bf[ni] = *(const short8*)&Bs[(wn + ni * 16 + lrow) * 32 + lk];
#pragma unroll
    for (int mi = 0; mi < 4; mi++)
#pragma unroll
      for (int ni = 0; ni < 4; ni++)
        acc[mi][ni] = MFMA_BF16(af[mi], bf[ni], acc[mi][ni]);
  }
#pragma unroll
  for (int mi = 0; mi < 4; mi++)
#pragma unroll
    for (int r = 0; r < 4; r++) {
      int m = mBase + wm + mi * 16 + lq + r;
      int b = m >> 11, t = m & 2047;
#pragma unroll
      for (int ni = 0; ni < 4; ni++) {
        int n = nBase + wn + ni * 16 + lrow;
        int h = n >> 6, dd = n & 63;
        D[(((size_t)(b * NHEADS + h)) * T_SEQ + t) * DHEAD + dd] =
            f2bf(acc[mi][ni][r] * scale);
      }
    }
}

// ---------------------------------------------------------------- attention
// Balanced snake: 64-row Q-tiles qt' in [0,32); block j handles {j, 31-j} ->
// exactly 33 kv64-iters per block. grid (16,32), 256 thr = 4 waves; wave owns
// 16 q-rows. DPP softmax reductions (no DS shuffles). LDS 27.6 KB.
__global__ __launch_bounds__(256) void attn_snake(
    const u16* __restrict__ Qg, const u16* __restrict__ Kg,
    const u16* __restrict__ Vg, u16* __restrict__ Ob) {
  __shared__ u16 smem[13824];  // 27648 B
  u16* Qs = smem;              // 64*72; aliased as Ps inside kv loop
  u16* Ps = smem;
  u16* Ks = smem + 4608;       // 64*72
  u16* Vt = smem + 9216;       // 64*72 (V transposed Vt[d][kv])

  const int tid = threadIdx.x;
  const int w = tid >> 6, lane = tid & 63;
  const int lrow = lane & 15;
  const int lk = (lane >> 4) << 3;
  const int lq = (lane >> 4) << 2;

  const int j = blockIdx.x;  // 0..15
  const int bh = blockIdx.y;
  const int b = bh >> 4, h = bh & 15;
  const u16* Qp = Qg + (size_t)bh * T_SEQ * DHEAD;
  const u16* Kp = Kg + (size_t)bh * T_SEQ * DHEAD;
  const u16* Vp = Vg + (size_t)bh * T_SEQ * DHEAD;

#pragma unroll
  for (int p = 0; p < 2; p++) {
    const int qt = p ? (31 - j) : j;
    const int qb = qt * 64;

    __syncthreads();  // prior phase's Ps readers done
    // stage Q tile (64 x 64, pre-scaled 1/8 in gemm_qkv)
#pragma unroll
    for (int i = 0; i < 2; i++) {
      int c = i * 256 + tid;
      int r = c >> 3, kk = (c & 7) << 3;
      *(uint4v*)&Qs[r * 72 + kk] =
          *(const uint4v*)&Qp[(size_t)(qb + r) * DHEAD + kk];
    }
    __syncthreads();
    short8 qf[2];
#pragma unroll
    for (int ks = 0; ks < 2; ks++)
      qf[ks] = *(const short8*)&Qs[(w * 16 + lrow) * 72 + ks * 32 + lk];

    float mst[4], lst[4];
    f32x4 oacc[4];
#pragma unroll
    for (int r = 0; r < 4; r++) { mst[r] = NEG_BIG; lst[r] = 0.f; }
#pragma unroll
    for (int nd = 0; nd < 4; nd++) oacc[nd] = (f32x4)0.0f;

    const int ntiles = qt + 1;
    for (int kt = 0; kt < ntiles; kt++) {
      const int kvb = kt * 64;
      __syncthreads();  // prior readers of Ks/Vt/Ps done (incl. qf loads)
      // stage K (64x64): 512 chunks, 2 per thread
#pragma unroll
      for (int i = 0; i < 2; i++) {
        int c = i * 256 + tid;
        int r = c >> 3, kk = (c & 7) << 3;
        *(uint4v*)&Ks[r * 72 + kk] =
            *(const uint4v*)&Kp[(size_t)(kvb + r) * DHEAD + kk];
      }
      // stage V transposed: thread gathers 8 kv of one d (coalesced u16 loads),
      // writes one b128. chunk (d, c8): wave-uniform c8 -> 128B/wave coalesced.
#pragma unroll
      for (int i = 0; i < 2; i++) {
        int t2 = i * 256 + tid;
        int d = t2 & 63, c8 = t2 >> 6;  // c8 in 0..7
        int kv0 = c8 << 3;
        short8 v8;
#pragma unroll
        for (int jj = 0; jj < 8; jj++)
          v8[jj] = (short)Vp[(size_t)(kvb + kv0 + jj) * DHEAD + d];
        *(short8*)&Vt[d * 72 + kv0] = v8;
      }
      __syncthreads();

      // S = Q K^T (wave: 16 x 64)
      f32x4 s[4];
#pragma unroll
      for (int nt = 0; nt < 4; nt++) {
        f32x4 a = (f32x4)0.0f;
#pragma unroll
        for (int ks = 0; ks < 2; ks++) {
          short8 kf = *(const short8*)&Ks[(nt * 16 + lrow) * 72 + ks * 32 + lk];
          a = MFMA_BF16(qf[ks], kf, a);
        }
        s[nt] = a;
      }

      // online softmax (per-row stats replicated across 16-lane groups, DPP)
      const int rowb = qb + w * 16 + lq;
      float corr[4], lt[4];
#pragma unroll
      for (int r = 0; r < 4; r++) {
        float mx = NEG_BIG;
#pragma unroll
        for (int nt = 0; nt < 4; nt++) {
          int col = kvb + nt * 16 + lrow;
          float sv = s[nt][r];
          if (col > rowb + r) sv = NEG_BIG;
          s[nt][r] = sv;
          mx = fmaxf(mx, sv);
        }
        mx = dpp16_max(mx);
        float mn = fmaxf(mst[r], mx);
        corr[r] = __expf(mst[r] - mn);
        mst[r] = mn;
        float ls = 0.f;
#pragma unroll
        for (int nt = 0; nt < 4; nt++) {
          float pp = __expf(s[nt][r] - mn);
          s[nt][r] = pp;
          ls += pp;
        }
        lt[r] = dpp16_sum(ls);
      }
#pragma unroll
      for (int r = 0; r < 4; r++) {
        lst[r] = corr[r] * lst[r] + lt[r];
#pragma unroll
        for (int nd = 0; nd < 4; nd++) oacc[nd][r] *= corr[r];
#pragma unroll
        for (int nt = 0; nt < 4; nt++)
          Ps[(w * 16 + lq + r) * 72 + nt * 16 + lrow] = f2bf(s[nt][r]);
      }

      // O += P @ V (P wave-private rows; same-wave LDS ordering)
#pragma unroll
      for (int ks = 0; ks < 2; ks++) {
        short8 vf[4];
#pragma unroll
        for (int nd = 0; nd < 4; nd++)
          vf[nd] = *(const short8*)&Vt[(nd * 16 + lrow) * 72 + ks * 32 + lk];
        short8 pf = *(const short8*)&Ps[(w * 16 + lrow) * 72 + ks * 32 + lk];
#pragma unroll
        for (int nd = 0; nd < 4; nd++)
          oacc[nd] = MFMA_BF16(pf, vf[nd], oacc[nd]);
      }
    }

    // normalize + write O bf16 (b, t, h*64+d)
#pragma unroll
    for (int r = 0; r < 4; r++) {
      int t = qb + w * 16 + lq + r;
      float inv = 1.f / lst[r];
#pragma unroll
      for (int nd = 0; nd < 4; nd++)
        Ob[((size_t)(b * T_SEQ + t)) * DMODEL + h * DHEAD + nd * 16 + lrow] =
            f2bf(oacc[nd][r] * inv);
    }
  }
}

// ---------------------------------------------------------------- out proj (bf16)
__global__ __launch_bounds__(256) void gemm_out_bf(const u16* __restrict__ O,
                                                   const u16* __restrict__ Wo,
                                                   float* __restrict__ Out) {
  __shared__ u16 As[128 * 32];
  __shared__ u16 Bs[128 * 32];
  const int tid = threadIdx.x, lane = tid & 63, w = tid >> 6;
  const int wm = (w >> 1) * 64, wn = (w & 1) * 64;
  const int lrow = lane & 15;
  const int lk = (lane >> 4) << 3;
  const int lq = (lane >> 4) << 2;
  const int mBase = blockIdx.x * 128, nBase = blockIdx.y * 128;

  f32x4 acc[4][4];
#pragma unroll
  for (int mi = 0; mi < 4; mi++)
#pragma unroll
    for (int ni = 0; ni < 4; ni++) acc[mi][ni] = (f32x4)0.0f;

  for (int k0 = 0; k0 < 1024; k0 += 32) {
    __syncthreads();
#pragma unroll
    for (int i = 0; i < 2; i++) {
      int c = i * 256 + tid;
      int r = c >> 2, kk = (c & 3) << 3;
      *(uint4v*)&As[c * 8] = *(const uint4v*)&O[(size_t)(mBase + r) * 1024 + k0 + kk];
      *(uint4v*)&Bs[c * 8] = *(const uint4v*)&Wo[(size_t)(nBase + r) * 1024 + k0 + kk];
    }
    __syncthreads();
    short8 af[4], bf[4];
#pragma unroll
    for (int mi = 0; mi < 4; mi++)
      af[mi] = *(const short8*)&As[(wm + mi * 16 + lrow) * 32 + lk];
#pragma unroll
    for (int ni = 0; ni < 4; ni++)
      bf[ni] = *(const short8*)&Bs[(wn + ni * 16 + lrow) * 32 + lk];
#pragma unroll
    for (int mi = 0; mi < 4; mi++)
#pragma unroll
      for (int ni = 0; ni < 4; ni++)
        acc[mi][ni] = MFMA_BF16(af[mi], bf[ni], acc[mi][ni]);
  }
#pragma unroll
  for (int mi = 0; mi < 4; mi++)
#pragma unroll
    for (int r = 0; r < 4; r++) {
      int m = mBase + wm + mi * 16 + lq + r;
#pragma unroll
      for (int ni = 0; ni < 4; ni++)
        Out[(size_t)m * DMODEL + nBase + wn + ni * 16 + lrow] = acc[mi][ni][r];
    }
}

// ---------------------------------------------------------------- launch
extern "C" void kernel_launch(void* const* d_in, const int* in_sizes, int n_in,
                              void* d_out, int out_size, void* d_ws,
                              size_t ws_size, hipStream_t stream) {
  const float* x = (const float*)d_in[0];
  const float* Wq = (const float*)d_in[1];
  const float* Wk = (const float*)d_in[2];
  const float* Wv = (const float*)d_in[3];
  const float* Wo = (const float*)d_in[4];
  float* out = (float*)d_out;

  u16* xh = (u16*)d_ws;      // 4M elems
  u16* wqh = xh + 4194304;   // 1M each
  u16* wkh = wqh + 1048576;
  u16* wvh = wkh + 1048576;
  u16* woh = wvh + 1048576;
  u16* Q = woh + 1048576;    // 4M each
  u16* K = Q + 4194304;
  u16* V = K + 4194304;
  u16* O = V + 4194304;      // total 48 MB (ws_size >= 48MB verified in r7)

  cvt_all<<<dim3(4096), 256, 0, stream>>>(x, Wq, Wk, Wv, Wo, xh, wqh, wkh, wvh, woh);
  gemm_qkv<<<dim3(32, 8, 3), 256, 0, stream>>>(xh, wqh, wkh, wvh, Q, K, V);
  attn_snake<<<dim3(16, 32), 256, 0, stream>>>(Q, K, V, O);
  gemm_out_bf<<<dim3(32, 8), 256, 0, stream>>>(O, woh, out);
}

// Round 9
// 196.306 us; speedup vs baseline: 6.3966x; 1.0630x over previous
//
#include <hip/hip_runtime.h>
#include <hip/hip_bf16.h>

typedef __attribute__((ext_vector_type(8))) short short8;
typedef __attribute__((ext_vector_type(4))) float f32x4;
typedef __attribute__((ext_vector_type(2))) unsigned int uint2v;
typedef __attribute__((ext_vector_type(4))) unsigned int uint4v;
typedef unsigned short u16;

#define MFMA_BF16(a, b, c) __builtin_amdgcn_mfma_f32_16x16x32_bf16(a, b, c, 0, 0, 0)

#define T_SEQ 2048
#define DMODEL 1024
#define NHEADS 16
#define DHEAD 64
#define NEG_BIG (-30000.0f)
#define QSCALE 0.1803368801111f  // 0.125 * log2(e): softmax in exp2 domain

#if __has_builtin(__builtin_amdgcn_exp2f)
#define EXP2(x) __builtin_amdgcn_exp2f(x)
#else
#define EXP2(x) exp2f(x)
#endif

__device__ __forceinline__ unsigned bfr(unsigned u) {
  return (u + 0x7fffu + ((u >> 16) & 1u)) >> 16;
}
__device__ __forceinline__ uint4v ld8bf(const float* __restrict__ p) {
  const uint4v a = *(const uint4v*)p;
  const uint4v b = *(const uint4v*)(p + 4);
  uint4v r;
  r[0] = bfr(a[0]) | (bfr(a[1]) << 16);
  r[1] = bfr(a[2]) | (bfr(a[3]) << 16);
  r[2] = bfr(b[0]) | (bfr(b[1]) << 16);
  r[3] = bfr(b[2]) | (bfr(b[3]) << 16);
  return r;
}
__device__ __forceinline__ u16 f2bf(float f) {
  unsigned u = __float_as_uint(f);
  u += 0x7fffu + ((u >> 16) & 1u);
  return (u16)(u >> 16);
}
// async global->LDS DMA, 16B per lane; lds dest must be uniform-base + lane*16
__device__ __forceinline__ void gld16(const u16* g, u16* l) {
  __builtin_amdgcn_global_load_lds(
      (const __attribute__((address_space(1))) unsigned int*)g,
      (__attribute__((address_space(3))) unsigned int*)l, 16, 0, 0);
}

// ---------------------------------------------------------------- cvt fp32->bf16
__global__ __launch_bounds__(256) void cvt_all(
    const float* __restrict__ x, const float* __restrict__ wq,
    const float* __restrict__ wk, const float* __restrict__ wv,
    const float* __restrict__ wo, u16* __restrict__ xh, u16* __restrict__ wqh,
    u16* __restrict__ wkh, u16* __restrict__ wvh, u16* __restrict__ woh) {
  int bi = blockIdx.x;
  const float* s;
  u16* d;
  size_t base;
  if (bi < 2048) {
    s = x; d = xh; base = (size_t)bi * 2048;
  } else {
    int k = (bi - 2048) >> 9;
    int r = (bi - 2048) & 511;
    s = (k == 0) ? wq : (k == 1) ? wk : (k == 2) ? wv : wo;
    d = (k == 0) ? wqh : (k == 1) ? wkh : (k == 2) ? wvh : woh;
    base = (size_t)r * 2048;
  }
  size_t i = base + (size_t)threadIdx.x * 8;
  *(uint4v*)&d[i] = ld8bf(&s[i]);
}

// ---------------------------------------------------------------- QKV proj (bf16)
// grid (32,8,3): z=0 Q (pre-scaled by 0.125*log2e), z=1 K -> (b,h,t,d);
// z=2 V -> TRANSPOSED (b,h,d,t). global_load_lds staging.
__global__ __launch_bounds__(256) void gemm_qkv(
    const u16* __restrict__ X, const u16* __restrict__ Wq,
    const u16* __restrict__ Wk, const u16* __restrict__ Wv,
    u16* __restrict__ Qo, u16* __restrict__ Ko, u16* __restrict__ Vo) {
  __shared__ __attribute__((aligned(16))) u16 As[128 * 32];
  __shared__ __attribute__((aligned(16))) u16 Bs[128 * 32];
  const int tid = threadIdx.x, lane = tid & 63, w = tid >> 6;
  const int wm = (w >> 1) * 64, wn = (w & 1) * 64;
  const int lrow = lane & 15;
  const int lk = (lane >> 4) << 3;
  const int lq = (lane >> 4) << 2;
  const int mBase = blockIdx.x * 128, nBase = blockIdx.y * 128;
  const u16* Bt = (blockIdx.z == 0) ? Wq : (blockIdx.z == 1) ? Wk : Wv;
  u16* D = (blockIdx.z == 0) ? Qo : (blockIdx.z == 1) ? Ko : Vo;
  const float scale = (blockIdx.z == 0) ? QSCALE : 1.0f;

  f32x4 acc[4][4];
#pragma unroll
  for (int mi = 0; mi < 4; mi++)
#pragma unroll
    for (int ni = 0; ni < 4; ni++) acc[mi][ni] = (f32x4)0.0f;

  for (int k0 = 0; k0 < 1024; k0 += 32) {
    __syncthreads();
#pragma unroll
    for (int i = 0; i < 2; i++) {
      int c = i * 256 + tid;
      int r = c >> 2, kk = (c & 3) << 3;
      gld16(&X[(size_t)(mBase + r) * 1024 + k0 + kk], &As[c * 8]);
      gld16(&Bt[(size_t)(nBase + r) * 1024 + k0 + kk], &Bs[c * 8]);
    }
    __syncthreads();
    short8 af[4], bf[4];
#pragma unroll
    for (int mi = 0; mi < 4; mi++)
      af[mi] = *(const short8*)&As[(wm + mi * 16 + lrow) * 32 + lk];
#pragma unroll
    for (int ni = 0; ni < 4; ni++)
      bf[ni] = *(const short8*)&Bs[(wn + ni * 16 + lrow) * 32 + lk];
#pragma unroll
    for (int mi = 0; mi < 4; mi++)
#pragma unroll
      for (int ni = 0; ni < 4; ni++)
        acc[mi][ni] = MFMA_BF16(af[mi], bf[ni], acc[mi][ni]);
  }
  const int vz = (blockIdx.z == 2);
#pragma unroll
  for (int mi = 0; mi < 4; mi++)
#pragma unroll
    for (int r = 0; r < 4; r++) {
      int m = mBase + wm + mi * 16 + lq + r;
      int b = m >> 11, t = m & 2047;
#pragma unroll
      for (int ni = 0; ni < 4; ni++) {
        int n = nBase + wn + ni * 16 + lrow;
        int h = n >> 6, dd = n & 63;
        size_t idx = vz ? (((size_t)((b * NHEADS + h) * DHEAD + dd)) * T_SEQ + t)
                        : ((((size_t)(b * NHEADS + h)) * T_SEQ + t) * DHEAD + dd);
        D[idx] = f2bf(acc[mi][ni][r] * scale);
      }
    }
}

// ---------------------------------------------------------------- attention
// Balanced snake over 64-row Q-tiles; block j handles {j, 31-j}. 256 thr = 4
// waves, wave owns 16 q-rows. S^T formulation: mfma(kf,qf) -> col=lane&15=q,
// so softmax stats are per-lane scalars (in-lane tree + 2 shfl_xor).
// V pre-transposed in ws (b,h,d,t). exp2-domain softmax (Q pre-scaled).
__global__ __launch_bounds__(256) void attn_snake(
    const u16* __restrict__ Qg, const u16* __restrict__ Kg,
    const u16* __restrict__ Vtg, u16* __restrict__ Ob) {
  __shared__ __attribute__((aligned(16))) u16 smem[13824];  // 27648 B
  u16* Qs = smem;         // 64*72; aliased as Ps (wave-private rows) in kv loop
  u16* Ps = smem;
  u16* Ks = smem + 4608;  // 64*72
  u16* Vt = smem + 9216;  // 64*72: Vt[d][kv]

  const int tid = threadIdx.x;
  const int w = tid >> 6, lane = tid & 63;
  const int lrow = lane & 15;
  const int quad = lane >> 4;
  const int lk = quad << 3;
  const int q_local = w * 16 + lrow;  // this lane's q-row within the 64-tile

  const int j = blockIdx.x;  // 0..15
  const int bh = blockIdx.y;
  const int b = bh >> 4, h = bh & 15;
  const u16* Qp = Qg + (size_t)bh * T_SEQ * DHEAD;
  const u16* Kp = Kg + (size_t)bh * T_SEQ * DHEAD;
  const u16* Vp = Vtg + (size_t)bh * DHEAD * T_SEQ;

#pragma unroll
  for (int p = 0; p < 2; p++) {
    const int qt = p ? (31 - j) : j;
    const int qb = qt * 64;

    __syncthreads();  // prior phase's Ps readers done
#pragma unroll
    for (int i = 0; i < 2; i++) {  // stage Q (64x64)
      int c = i * 256 + tid;
      int r = c >> 3, kk = (c & 7) << 3;
      *(uint4v*)&Qs[r * 72 + kk] =
          *(const uint4v*)&Qp[(size_t)(qb + r) * DHEAD + kk];
    }
    __syncthreads();
    short8 qf[2];
#pragma unroll
    for (int ks = 0; ks < 2; ks++)
      qf[ks] = *(const short8*)&Qs[q_local * 72 + ks * 32 + lk];

    float mst = NEG_BIG, lst = 0.f;
    f32x4 oacc[4];
#pragma unroll
    for (int nd = 0; nd < 4; nd++) oacc[nd] = (f32x4)0.0f;

    const int ntiles = qt + 1;
    for (int kt = 0; kt < ntiles; kt++) {
      const int kvb = kt * 64;
      __syncthreads();  // prior kf/vf readers done (qf loads done pre-loop)
#pragma unroll
      for (int i = 0; i < 2; i++) {  // stage K rows (t-major) + V rows (d-major)
        int c = i * 256 + tid;
        int r = c >> 3, kk = (c & 7) << 3;
        *(uint4v*)&Ks[r * 72 + kk] =
            *(const uint4v*)&Kp[(size_t)(kvb + r) * DHEAD + kk];
        *(uint4v*)&Vt[r * 72 + kk] =
            *(const uint4v*)&Vp[(size_t)r * T_SEQ + kvb + kk];
      }
      __syncthreads();

      // S^T: s[kvt] has col=lane&15=q_local, row(quad*4+r)=kv within tile
      f32x4 s[4];
#pragma unroll
      for (int kvt = 0; kvt < 4; kvt++) {
        f32x4 a = (f32x4)0.0f;
#pragma unroll
        for (int ks = 0; ks < 2; ks++) {
          short8 kf = *(const short8*)&Ks[(kvt * 16 + lrow) * 72 + ks * 32 + lk];
          a = MFMA_BF16(kf, qf[ks], a);
        }
        s[kvt] = a;
      }

      if (kt == qt) {  // causal mask: only the diagonal tile needs it
#pragma unroll
        for (int kvt = 0; kvt < 4; kvt++)
#pragma unroll
          for (int r = 0; r < 4; r++)
            if (kvt * 16 + quad * 4 + r > q_local) s[kvt][r] = NEG_BIG;
      }

      // online softmax, per-lane scalar stats (one q-row per lane)
      float mx = s[0][0];
#pragma unroll
      for (int kvt = 0; kvt < 4; kvt++)
#pragma unroll
        for (int r = 0; r < 4; r++) mx = fmaxf(mx, s[kvt][r]);
      mx = fmaxf(mx, __shfl_xor(mx, 16));
      mx = fmaxf(mx, __shfl_xor(mx, 32));
      float mn = fmaxf(mst, mx);
      float corr = EXP2(mst - mn);
      mst = mn;
      float ls = 0.f;
#pragma unroll
      for (int kvt = 0; kvt < 4; kvt++)
#pragma unroll
        for (int r = 0; r < 4; r++) {
          float pv = EXP2(s[kvt][r] - mn);
          s[kvt][r] = pv;
          ls += pv;
        }
      ls += __shfl_xor(ls, 16);
      ls += __shfl_xor(ls, 32);
      lst = corr * lst + ls;
#pragma unroll
      for (int nd = 0; nd < 4; nd++) oacc[nd] *= corr;

      // P store: row q_local, 4 consecutive kv per kvt -> packed b64 writes.
      // Truncation (P in [0,1], rel err < 0.4%) saves ~48 VALU/iter.
#pragma unroll
      for (int kvt = 0; kvt < 4; kvt++) {
        uint2v pk;
        pk[0] = (__float_as_uint(s[kvt][0]) >> 16) |
                (__float_as_uint(s[kvt][1]) & 0xffff0000u);
        pk[1] = (__float_as_uint(s[kvt][2]) >> 16) |
                (__float_as_uint(s[kvt][3]) & 0xffff0000u);
        *(uint2v*)&Ps[q_local * 72 + kvt * 16 + quad * 4] = pk;
      }

      // O^T += V^T P^T: mfma(vf, pf) -> col=q_local, row=d within tile
#pragma unroll
      for (int ks = 0; ks < 2; ks++) {
        short8 pf = *(const short8*)&Ps[q_local * 72 + ks * 32 + lk];
#pragma unroll
        for (int nd = 0; nd < 4; nd++) {
          short8 vf = *(const short8*)&Vt[(nd * 16 + lrow) * 72 + ks * 32 + lk];
          oacc[nd] = MFMA_BF16(vf, pf, oacc[nd]);
        }
      }
    }

    // epilogue: lane owns q-row qb+q_local fully; d = nd*16 + quad*4 + r
    float inv = 1.f / lst;
    size_t rowbase = ((size_t)(b * T_SEQ + qb + q_local)) * DMODEL + h * DHEAD;
#pragma unroll
    for (int nd = 0; nd < 4; nd++) {
      uint2v pk;
      pk[0] = (unsigned)f2bf(oacc[nd][0] * inv) |
              ((unsigned)f2bf(oacc[nd][1] * inv) << 16);
      pk[1] = (unsigned)f2bf(oacc[nd][2] * inv) |
              ((unsigned)f2bf(oacc[nd][3] * inv) << 16);
      *(uint2v*)&Ob[rowbase + nd * 16 + quad * 4] = pk;
    }
  }
}

// ---------------------------------------------------------------- out proj (bf16)
__global__ __launch_bounds__(256) void gemm_out_bf(const u16* __restrict__ O,
                                                   const u16* __restrict__ Wo,
                                                   float* __restrict__ Out) {
  __shared__ __attribute__((aligned(16))) u16 As[128 * 32];
  __shared__ __attribute__((aligned(16))) u16 Bs[128 * 32];
  const int tid = threadIdx.x, lane = tid & 63, w = tid >> 6;
  const int wm = (w >> 1) * 64, wn = (w & 1) * 64;
  const int lrow = lane & 15;
  const int lk = (lane >> 4) << 3;
  const int lq = (lane >> 4) << 2;
  const int mBase = blockIdx.x * 128, nBase = blockIdx.y * 128;

  f32x4 acc[4][4];
#pragma unroll
  for (int mi = 0; mi < 4; mi++)
#pragma unroll
    for (int ni = 0; ni < 4; ni++) acc[mi][ni] = (f32x4)0.0f;

  for (int k0 = 0; k0 < 1024; k0 += 32) {
    __syncthreads();
#pragma unroll
    for (int i = 0; i < 2; i++) {
      int c = i * 256 + tid;
      int r = c >> 2, kk = (c & 3) << 3;
      gld16(&O[(size_t)(mBase + r) * 1024 + k0 + kk], &As[c * 8]);
      gld16(&Wo[(size_t)(nBase + r) * 1024 + k0 + kk], &Bs[c * 8]);
    }
    __syncthreads();
    short8 af[4], bf[4];
#pragma unroll
    for (int mi = 0; mi < 4; mi++)
      af[mi] = *(const short8*)&As[(wm + mi * 16 + lrow) * 32 + lk];
#pragma unroll
    for (int ni = 0; ni < 4; ni++)
      bf[ni] = *(const short8*)&Bs[(wn + ni * 16 + lrow) * 32 + lk];
#pragma unroll
    for (int mi = 0; mi < 4; mi++)
#pragma unroll
      for (int ni = 0; ni < 4; ni++)
        acc[mi][ni] = MFMA_BF16(af[mi], bf[ni], acc[mi][ni]);
  }
#pragma unroll
  for (int mi = 0; mi < 4; mi++)
#pragma unroll
    for (int r = 0; r < 4; r++) {
      int m = mBase + wm + mi * 16 + lq + r;
#pragma unroll
      for (int ni = 0; ni < 4; ni++)
        Out[(size_t)m * DMODEL + nBase + wn + ni * 16 + lrow] = acc[mi][ni][r];
    }
}

// ---------------------------------------------------------------- launch
extern "C" void kernel_launch(void* const* d_in, const int* in_sizes, int n_in,
                              void* d_out, int out_size, void* d_ws,
                              size_t ws_size, hipStream_t stream) {
  const float* x = (const float*)d_in[0];
  const float* Wq = (const float*)d_in[1];
  const float* Wk = (const float*)d_in[2];
  const float* Wv = (const float*)d_in[3];
  const float* Wo = (const float*)d_in[4];
  float* out = (float*)d_out;

  u16* xh = (u16*)d_ws;      // 4M elems
  u16* wqh = xh + 4194304;   // 1M each
  u16* wkh = wqh + 1048576;
  u16* wvh = wkh + 1048576;
  u16* woh = wvh + 1048576;
  u16* Q = woh + 1048576;    // 4M each; V stored transposed (b,h,d,t)
  u16* K = Q + 4194304;
  u16* V = K + 4194304;
  u16* O = V + 4194304;      // total 48 MB (verified fits in r7/r8)

  cvt_all<<<dim3(4096), 256, 0, stream>>>(x, Wq, Wk, Wv, Wo, xh, wqh, wkh, wvh, woh);
  gemm_qkv<<<dim3(32, 8, 3), 256, 0, stream>>>(xh, wqh, wkh, wvh, Q, K, V);
  attn_snake<<<dim3(16, 32), 256, 0, stream>>>(Q, K, V, O);
  gemm_out_bf<<<dim3(32, 8), 256, 0, stream>>>(O, woh, out);
}